// Round 1
// baseline (1385.724 us; speedup 1.0000x reference)
//
#include <hip/hip_runtime.h>
#include <hip/hip_bf16.h>

// Hetero-SAGE: CSR-sorted segment-mean aggregation + fp32 tiled GEMMs + fused edge MLP.
#define NUV 100000
#define NMV 20000
#define FUV 64
#define FMV 32
#define HD  128
#define NEV 1000000
#define ETV 500000

// ---------------- CSR construction ----------------
__global__ __launch_bounds__(256) void k_hist(const int* __restrict__ col, int* __restrict__ off, int n) {
  int stride = gridDim.x * blockDim.x;
  for (int i = blockIdx.x * blockDim.x + threadIdx.x; i < n; i += stride)
    atomicAdd(&off[col[i] + 1], 1);
}

// one-block chunked exclusive scan (off[0]=0 pre-zeroed; counts at off[1..n] -> prefix sums)
__global__ __launch_bounds__(1024) void k_scan2(int* off_a, int na, int* off_b, int nb) {
  int* off = blockIdx.x ? off_b : off_a;
  int n    = blockIdx.x ? nb    : na;
  __shared__ int wsum[16];
  __shared__ int carry;
  int tid = threadIdx.x, lane = tid & 63, w = tid >> 6;
  if (tid == 0) carry = 0;
  __syncthreads();
  for (int base = 1; base <= n; base += 1024) {
    int i = base + tid;
    int v = (i <= n) ? off[i] : 0;
    int s = v;
    #pragma unroll
    for (int d = 1; d < 64; d <<= 1) { int t = __shfl_up(s, d); if (lane >= d) s += t; }
    if (lane == 63) wsum[w] = s;
    __syncthreads();
    if (w == 0 && lane < 16) {
      int ws_ = wsum[lane];
      #pragma unroll
      for (int d = 1; d < 16; d <<= 1) { int t = __shfl_up(ws_, d); if (lane >= d) ws_ += t; }
      wsum[lane] = ws_;
    }
    __syncthreads();
    int incl = s + (w ? wsum[w - 1] : 0) + carry;
    if (i <= n) off[i] = incl;
    __syncthreads();
    if (tid == 1023) carry = incl;
    __syncthreads();
  }
}

__global__ __launch_bounds__(256) void k_scatter(const int* __restrict__ col, const int* __restrict__ row,
                                                 const int* __restrict__ off, int* __restrict__ cur,
                                                 int* __restrict__ srow, int n) {
  int stride = gridDim.x * blockDim.x;
  for (int i = blockIdx.x * blockDim.x + threadIdx.x; i < n; i += stride) {
    int c = col[i];
    int p = atomicAdd(&cur[c], 1);
    srow[off[c] + p] = row[i];
  }
}

// ---------------- segment-mean aggregation (one wave per destination) ----------------
__global__ __launch_bounds__(256) void k_agg64(const int* __restrict__ off, const int* __restrict__ srow,
                                               const float* __restrict__ xs, float* __restrict__ agg, int ndst) {
  int wid = (blockIdx.x * 256 + threadIdx.x) >> 6;
  int lane = threadIdx.x & 63;
  if (wid >= ndst) return;
  int s = off[wid], t = off[wid + 1];
  float acc = 0.f;
  for (int j = s; j < t; ++j) acc += xs[(size_t)srow[j] * 64 + lane];
  agg[(size_t)wid * 64 + lane] = acc / (float)max(t - s, 1);
}

__global__ __launch_bounds__(256) void k_agg32(const int* __restrict__ off, const int* __restrict__ srow,
                                               const float* __restrict__ xs, float* __restrict__ agg, int ndst) {
  int wid = (blockIdx.x * 256 + threadIdx.x) >> 6;
  int lane = threadIdx.x & 63;
  if (wid >= ndst) return;
  int s = off[wid], t = off[wid + 1];
  int half = lane >> 5, f = lane & 31;
  float acc = 0.f;
  for (int j = s + half; j < t; j += 2) acc += xs[(size_t)srow[j] * 32 + f];
  acc += __shfl_xor(acc, 32);
  if (half == 0) agg[(size_t)wid * 32 + f] = acc / (float)max(t - s, 1);
}

__global__ __launch_bounds__(256) void k_agg128(const int* __restrict__ off, const int* __restrict__ srow,
                                                const float* __restrict__ xs, float* __restrict__ agg, int ndst) {
  int wid = (blockIdx.x * 256 + threadIdx.x) >> 6;
  int lane = threadIdx.x & 63;
  if (wid >= ndst) return;
  int s = off[wid], t = off[wid + 1];
  const float2* x2 = (const float2*)xs;
  float ax = 0.f, ay = 0.f;
  for (int j = s; j < t; ++j) {
    float2 v = x2[(size_t)srow[j] * 64 + lane];
    ax += v.x; ay += v.y;
  }
  float inv = 1.f / (float)max(t - s, 1);
  ((float2*)agg)[(size_t)wid * 64 + lane] = make_float2(ax * inv, ay * inv);
}

// ---------------- dual-input GEMM: out[m,o] = act(A@Wa + B@Wb + bias) ----------------
// M-tile=32, N=128. 256 threads: tx=tid&31 -> o=tx*4.. ; ty=tid>>5 -> m=ty*4..
template <int KA, int KB, bool RELU>
__global__ __launch_bounds__(256) void k_gemm_dual(const float* __restrict__ A, const float* __restrict__ B,
                                                   const float* __restrict__ Wa, const float* __restrict__ Wb,
                                                   const float* __restrict__ bias, float* __restrict__ out, int nd) {
  __shared__ float At[KA * 32];
  __shared__ float Bt[KB * 32];
  int tid = threadIdx.x;
  int m0 = blockIdx.x * 32;
  {
    int m = tid & 31, kq = tid >> 5;
    const float* Ar = A + (size_t)(m0 + m) * KA;
    for (int k0 = kq * 4; k0 < KA; k0 += 32) {
      float4 v = *(const float4*)(Ar + k0);
      At[(k0 + 0) * 32 + m] = v.x; At[(k0 + 1) * 32 + m] = v.y;
      At[(k0 + 2) * 32 + m] = v.z; At[(k0 + 3) * 32 + m] = v.w;
    }
    const float* Br = B + (size_t)(m0 + m) * KB;
    for (int k0 = kq * 4; k0 < KB; k0 += 32) {
      float4 v = *(const float4*)(Br + k0);
      Bt[(k0 + 0) * 32 + m] = v.x; Bt[(k0 + 1) * 32 + m] = v.y;
      Bt[(k0 + 2) * 32 + m] = v.z; Bt[(k0 + 3) * 32 + m] = v.w;
    }
  }
  __syncthreads();
  int tx = tid & 31, ty = tid >> 5;
  float acc[4][4] = {};
  #pragma unroll 4
  for (int k = 0; k < KA; ++k) {
    float4 wv = *(const float4*)(Wa + k * 128 + tx * 4);
    float4 av = *(const float4*)(&At[k * 32 + ty * 4]);
    float am[4] = {av.x, av.y, av.z, av.w};
    float wo[4] = {wv.x, wv.y, wv.z, wv.w};
    #pragma unroll
    for (int mi = 0; mi < 4; ++mi)
      #pragma unroll
      for (int oi = 0; oi < 4; ++oi) acc[mi][oi] += am[mi] * wo[oi];
  }
  #pragma unroll 4
  for (int k = 0; k < KB; ++k) {
    float4 wv = *(const float4*)(Wb + k * 128 + tx * 4);
    float4 av = *(const float4*)(&Bt[k * 32 + ty * 4]);
    float am[4] = {av.x, av.y, av.z, av.w};
    float wo[4] = {wv.x, wv.y, wv.z, wv.w};
    #pragma unroll
    for (int mi = 0; mi < 4; ++mi)
      #pragma unroll
      for (int oi = 0; oi < 4; ++oi) acc[mi][oi] += am[mi] * wo[oi];
  }
  float4 bv = *(const float4*)(bias + tx * 4);
  float bb[4] = {bv.x, bv.y, bv.z, bv.w};
  #pragma unroll
  for (int mi = 0; mi < 4; ++mi) {
    float4 o;
    float* op = (float*)&o;
    #pragma unroll
    for (int oi = 0; oi < 4; ++oi) {
      float v = acc[mi][oi] + bb[oi];
      if (RELU) v = v > 0.f ? v : 0.f;
      op[oi] = v;
    }
    *(float4*)(out + (size_t)(m0 + ty * 4 + mi) * 128 + tx * 4) = o;
  }
}

// ---------------- fused edge classifier: out = Wc2 . relu(Wc1^T [zu;zm] + bc1) + bc2 ----------------
__global__ __launch_bounds__(256) void k_classifier(const float* __restrict__ zu_, const float* __restrict__ zm_,
                                                    const int* __restrict__ row_t, const int* __restrict__ col_t,
                                                    const float* __restrict__ Wc1, const float* __restrict__ bc1,
                                                    const float* __restrict__ Wc2, const float* __restrict__ bc2,
                                                    float* __restrict__ out) {
  __shared__ float At[256 * 32];  // 32KB: K=256 transposed, 32 edges
  __shared__ float w2s[128], b1s[128];
  int tid = threadIdx.x;
  if (tid < 128) { w2s[tid] = Wc2[tid]; b1s[tid] = bc1[tid]; }
  int e0 = blockIdx.x * 32;
  {
    int j = tid & 31, kq = tid >> 5;
    const float* zu = zu_ + (size_t)row_t[e0 + j] * 128;
    const float* zm = zm_ + (size_t)col_t[e0 + j] * 128;
    for (int k0 = kq * 4; k0 < 128; k0 += 32) {
      float4 v = *(const float4*)(zu + k0);
      At[(k0 + 0) * 32 + j] = v.x; At[(k0 + 1) * 32 + j] = v.y;
      At[(k0 + 2) * 32 + j] = v.z; At[(k0 + 3) * 32 + j] = v.w;
      float4 u = *(const float4*)(zm + k0);
      At[(128 + k0 + 0) * 32 + j] = u.x; At[(128 + k0 + 1) * 32 + j] = u.y;
      At[(128 + k0 + 2) * 32 + j] = u.z; At[(128 + k0 + 3) * 32 + j] = u.w;
    }
  }
  __syncthreads();
  int tx = tid & 31, ty = tid >> 5;
  float acc[4][4] = {};
  #pragma unroll 4
  for (int k = 0; k < 256; ++k) {
    float4 wv = *(const float4*)(Wc1 + k * 128 + tx * 4);
    float4 av = *(const float4*)(&At[k * 32 + ty * 4]);
    float am[4] = {av.x, av.y, av.z, av.w};
    float wo[4] = {wv.x, wv.y, wv.z, wv.w};
    #pragma unroll
    for (int mi = 0; mi < 4; ++mi)
      #pragma unroll
      for (int oi = 0; oi < 4; ++oi) acc[mi][oi] += am[mi] * wo[oi];
  }
  float bc2v = bc2[0];
  float res[4];
  #pragma unroll
  for (int mi = 0; mi < 4; ++mi) {
    float p = 0.f;
    #pragma unroll
    for (int oi = 0; oi < 4; ++oi) {
      int o = tx * 4 + oi;
      float h = acc[mi][oi] + b1s[o];
      h = h > 0.f ? h : 0.f;
      p += h * w2s[o];
    }
    #pragma unroll
    for (int d = 1; d < 32; d <<= 1) p += __shfl_xor(p, d);
    res[mi] = p;
  }
  if (tx == 0) {
    float4 o = make_float4(res[0] + bc2v, res[1] + bc2v, res[2] + bc2v, res[3] + bc2v);
    *(float4*)(out + e0 + ty * 4) = o;
  }
}

extern "C" void kernel_launch(void* const* d_in, const int* in_sizes, int n_in,
                              void* d_out, int out_size, void* d_ws, size_t ws_size,
                              hipStream_t stream) {
  const float* x_user  = (const float*)d_in[0];
  const float* x_merch = (const float*)d_in[1];
  const int* row_um = (const int*)d_in[2]; const int* col_um = (const int*)d_in[3];
  const int* row_mu = (const int*)d_in[4]; const int* col_mu = (const int*)d_in[5];
  const int* row_t  = (const int*)d_in[6]; const int* col_t  = (const int*)d_in[7];
  const float* W1l_um = (const float*)d_in[8];  const float* W1r_um = (const float*)d_in[9];  const float* b1_um = (const float*)d_in[10];
  const float* W1l_mu = (const float*)d_in[11]; const float* W1r_mu = (const float*)d_in[12]; const float* b1_mu = (const float*)d_in[13];
  const float* W2l_um = (const float*)d_in[14]; const float* W2r_um = (const float*)d_in[15]; const float* b2_um = (const float*)d_in[16];
  const float* W2l_mu = (const float*)d_in[17]; const float* W2r_mu = (const float*)d_in[18]; const float* b2_mu = (const float*)d_in[19];
  const float* Wc1 = (const float*)d_in[20]; const float* bc1 = (const float*)d_in[21];
  const float* Wc2 = (const float*)d_in[22]; const float* bc2 = (const float*)d_in[23];
  float* out = (float*)d_out;

  char* ws = (char*)d_ws;
  size_t p = 0;
  auto alloc = [&](size_t bytes) -> char* {
    char* r = ws + p;
    p = (p + bytes + 255) & ~(size_t)255;
    return r;
  };
  int* off_um = (int*)alloc((size_t)(NMV + 1) * 4);
  int* off_mu = (int*)alloc((size_t)(NUV + 1) * 4);
  int* cur_um = (int*)alloc((size_t)NMV * 4);
  int* cur_mu = (int*)alloc((size_t)NUV * 4);
  size_t zero_end = p;
  int* srow_um = (int*)alloc((size_t)NEV * 4);
  int* srow_mu = (int*)alloc((size_t)NEV * 4);
  float* agg_m = (float*)alloc((size_t)NMV * 128 * 4);  // layer1 [NM,64], layer2 [NM,128]; z_m aliases
  float* agg_u = (float*)alloc((size_t)NUV * 128 * 4);  // layer1 [NU,32], layer2 [NU,128]; z_u aliases
  float* h_m = (float*)alloc((size_t)NMV * 128 * 4);
  float* h_u = (float*)alloc((size_t)NUV * 128 * 4);
  float* z_m = agg_m;
  float* z_u = agg_u;
  if (p > ws_size) return;  // workspace too small: fail loudly via absmax

  hipMemsetAsync(d_ws, 0, zero_end, stream);
  // CSR for both edge types (reused by layer 1 and layer 2)
  k_hist<<<1024, 256, 0, stream>>>(col_um, off_um, NEV);
  k_hist<<<1024, 256, 0, stream>>>(col_mu, off_mu, NEV);
  k_scan2<<<2, 1024, 0, stream>>>(off_um, NMV, off_mu, NUV);
  k_scatter<<<1024, 256, 0, stream>>>(col_um, row_um, off_um, cur_um, srow_um, NEV);
  k_scatter<<<1024, 256, 0, stream>>>(col_mu, row_mu, off_mu, cur_mu, srow_mu, NEV);
  // layer 1
  k_agg64<<<(NMV + 3) / 4, 256, 0, stream>>>(off_um, srow_um, x_user, agg_m, NMV);
  k_gemm_dual<64, 32, true><<<NMV / 32, 256, 0, stream>>>(agg_m, x_merch, W1l_um, W1r_um, b1_um, h_m, NMV);
  k_agg32<<<(NUV + 3) / 4, 256, 0, stream>>>(off_mu, srow_mu, x_merch, agg_u, NUV);
  k_gemm_dual<32, 64, true><<<NUV / 32, 256, 0, stream>>>(agg_u, x_user, W1l_mu, W1r_mu, b1_mu, h_u, NUV);
  // layer 2 (z aliases agg: safe, each tile reads its rows before writing them)
  k_agg128<<<(NMV + 3) / 4, 256, 0, stream>>>(off_um, srow_um, h_u, agg_m, NMV);
  k_gemm_dual<128, 128, false><<<NMV / 32, 256, 0, stream>>>(agg_m, h_m, W2l_um, W2r_um, b2_um, z_m, NMV);
  k_agg128<<<(NUV + 3) / 4, 256, 0, stream>>>(off_mu, srow_mu, h_m, agg_u, NUV);
  k_gemm_dual<128, 128, false><<<NUV / 32, 256, 0, stream>>>(agg_u, h_u, W2l_mu, W2r_mu, b2_mu, z_u, NUV);
  // edge classifier
  k_classifier<<<ETV / 32, 256, 0, stream>>>(z_u, z_m, row_t, col_t, Wc1, bc1, Wc2, bc2, out);
}

// Round 2
// 1009.732 us; speedup vs baseline: 1.3724x; 1.3724x over previous
//
#include <hip/hip_runtime.h>
#include <hip/hip_bf16.h>

// Hetero-SAGE: CSR-sorted segment-mean aggregation + fp32 tiled GEMMs + bf16-MFMA edge MLP.
#define NUV 100000
#define NMV 20000
#define FUV 64
#define FMV 32
#define HD  128
#define NEV 1000000
#define ETV 500000

typedef unsigned short u16;
typedef __attribute__((ext_vector_type(8))) short s16x8;
typedef __attribute__((ext_vector_type(4))) float f32x4;
typedef __attribute__((ext_vector_type(4))) unsigned short u16x4;

__device__ inline u16 bf16r(float f) {  // RTNE float->bf16
  unsigned int b = __builtin_bit_cast(unsigned int, f);
  unsigned int r = b + 0x7fffu + ((b >> 16) & 1u);
  return (u16)(r >> 16);
}

// ---------------- CSR construction ----------------
__global__ __launch_bounds__(256) void k_hist(const int* __restrict__ col, int* __restrict__ off, int n) {
  int stride = gridDim.x * blockDim.x;
  for (int i = blockIdx.x * blockDim.x + threadIdx.x; i < n; i += stride)
    atomicAdd(&off[col[i] + 1], 1);
}

// one-block chunked exclusive scan (off[0]=0 pre-zeroed; counts at off[1..n] -> prefix sums)
__global__ __launch_bounds__(1024) void k_scan2(int* off_a, int na, int* off_b, int nb) {
  int* off = blockIdx.x ? off_b : off_a;
  int n    = blockIdx.x ? nb    : na;
  __shared__ int wsum[16];
  __shared__ int carry;
  int tid = threadIdx.x, lane = tid & 63, w = tid >> 6;
  if (tid == 0) carry = 0;
  __syncthreads();
  for (int base = 1; base <= n; base += 1024) {
    int i = base + tid;
    int v = (i <= n) ? off[i] : 0;
    int s = v;
    #pragma unroll
    for (int d = 1; d < 64; d <<= 1) { int t = __shfl_up(s, d); if (lane >= d) s += t; }
    if (lane == 63) wsum[w] = s;
    __syncthreads();
    if (w == 0 && lane < 16) {
      int ws_ = wsum[lane];
      #pragma unroll
      for (int d = 1; d < 16; d <<= 1) { int t = __shfl_up(ws_, d); if (lane >= d) ws_ += t; }
      wsum[lane] = ws_;
    }
    __syncthreads();
    int incl = s + (w ? wsum[w - 1] : 0) + carry;
    if (i <= n) off[i] = incl;
    __syncthreads();
    if (tid == 1023) carry = incl;
    __syncthreads();
  }
}

__global__ __launch_bounds__(256) void k_scatter(const int* __restrict__ col, const int* __restrict__ row,
                                                 const int* __restrict__ off, int* __restrict__ cur,
                                                 int* __restrict__ srow, int n) {
  int stride = gridDim.x * blockDim.x;
  for (int i = blockIdx.x * blockDim.x + threadIdx.x; i < n; i += stride) {
    int c = col[i];
    int p = atomicAdd(&cur[c], 1);
    srow[off[c] + p] = row[i];
  }
}

// ---------------- segment-mean aggregation (one wave per destination) ----------------
__global__ __launch_bounds__(256) void k_agg64(const int* __restrict__ off, const int* __restrict__ srow,
                                               const float* __restrict__ xs, float* __restrict__ agg, int ndst) {
  int wid = (blockIdx.x * 256 + threadIdx.x) >> 6;
  int lane = threadIdx.x & 63;
  if (wid >= ndst) return;
  int s = off[wid], t = off[wid + 1];
  float acc = 0.f;
  for (int j = s; j < t; ++j) acc += xs[(size_t)srow[j] * 64 + lane];
  agg[(size_t)wid * 64 + lane] = acc / (float)max(t - s, 1);
}

__global__ __launch_bounds__(256) void k_agg32(const int* __restrict__ off, const int* __restrict__ srow,
                                               const float* __restrict__ xs, float* __restrict__ agg, int ndst) {
  int wid = (blockIdx.x * 256 + threadIdx.x) >> 6;
  int lane = threadIdx.x & 63;
  if (wid >= ndst) return;
  int s = off[wid], t = off[wid + 1];
  int half = lane >> 5, f = lane & 31;
  float acc = 0.f;
  for (int j = s + half; j < t; j += 2) acc += xs[(size_t)srow[j] * 32 + f];
  acc += __shfl_xor(acc, 32);
  if (half == 0) agg[(size_t)wid * 32 + f] = acc / (float)max(t - s, 1);
}

__global__ __launch_bounds__(256) void k_agg128(const int* __restrict__ off, const int* __restrict__ srow,
                                                const float* __restrict__ xs, float* __restrict__ agg, int ndst) {
  int wid = (blockIdx.x * 256 + threadIdx.x) >> 6;
  int lane = threadIdx.x & 63;
  if (wid >= ndst) return;
  int s = off[wid], t = off[wid + 1];
  const float2* x2 = (const float2*)xs;
  float ax = 0.f, ay = 0.f;
  for (int j = s; j < t; ++j) {
    float2 v = x2[(size_t)srow[j] * 64 + lane];
    ax += v.x; ay += v.y;
  }
  float inv = 1.f / (float)max(t - s, 1);
  ((float2*)agg)[(size_t)wid * 64 + lane] = make_float2(ax * inv, ay * inv);
}

// ---------------- dual-input GEMM: out[m,o] = act(A@Wa + B@Wb + bias) ----------------
template <int KA, int KB, bool RELU>
__global__ __launch_bounds__(256) void k_gemm_dual(const float* __restrict__ A, const float* __restrict__ B,
                                                   const float* __restrict__ Wa, const float* __restrict__ Wb,
                                                   const float* __restrict__ bias, float* __restrict__ out, int nd) {
  __shared__ float At[KA * 32];
  __shared__ float Bt[KB * 32];
  int tid = threadIdx.x;
  int m0 = blockIdx.x * 32;
  {
    int m = tid & 31, kq = tid >> 5;
    const float* Ar = A + (size_t)(m0 + m) * KA;
    for (int k0 = kq * 4; k0 < KA; k0 += 32) {
      float4 v = *(const float4*)(Ar + k0);
      At[(k0 + 0) * 32 + m] = v.x; At[(k0 + 1) * 32 + m] = v.y;
      At[(k0 + 2) * 32 + m] = v.z; At[(k0 + 3) * 32 + m] = v.w;
    }
    const float* Br = B + (size_t)(m0 + m) * KB;
    for (int k0 = kq * 4; k0 < KB; k0 += 32) {
      float4 v = *(const float4*)(Br + k0);
      Bt[(k0 + 0) * 32 + m] = v.x; Bt[(k0 + 1) * 32 + m] = v.y;
      Bt[(k0 + 2) * 32 + m] = v.z; Bt[(k0 + 3) * 32 + m] = v.w;
    }
  }
  __syncthreads();
  int tx = tid & 31, ty = tid >> 5;
  float acc[4][4] = {};
  #pragma unroll 4
  for (int k = 0; k < KA; ++k) {
    float4 wv = *(const float4*)(Wa + k * 128 + tx * 4);
    float4 av = *(const float4*)(&At[k * 32 + ty * 4]);
    float am[4] = {av.x, av.y, av.z, av.w};
    float wo[4] = {wv.x, wv.y, wv.z, wv.w};
    #pragma unroll
    for (int mi = 0; mi < 4; ++mi)
      #pragma unroll
      for (int oi = 0; oi < 4; ++oi) acc[mi][oi] += am[mi] * wo[oi];
  }
  #pragma unroll 4
  for (int k = 0; k < KB; ++k) {
    float4 wv = *(const float4*)(Wb + k * 128 + tx * 4);
    float4 av = *(const float4*)(&Bt[k * 32 + ty * 4]);
    float am[4] = {av.x, av.y, av.z, av.w};
    float wo[4] = {wv.x, wv.y, wv.z, wv.w};
    #pragma unroll
    for (int mi = 0; mi < 4; ++mi)
      #pragma unroll
      for (int oi = 0; oi < 4; ++oi) acc[mi][oi] += am[mi] * wo[oi];
  }
  float4 bv = *(const float4*)(bias + tx * 4);
  float bb[4] = {bv.x, bv.y, bv.z, bv.w};
  #pragma unroll
  for (int mi = 0; mi < 4; ++mi) {
    float4 o;
    float* op = (float*)&o;
    #pragma unroll
    for (int oi = 0; oi < 4; ++oi) {
      float v = acc[mi][oi] + bb[oi];
      if (RELU) v = v > 0.f ? v : 0.f;
      op[oi] = v;
    }
    *(float4*)(out + (size_t)(m0 + ty * 4 + mi) * 128 + tx * 4) = o;
  }
}

// ---------------- bf16 prep ----------------
__global__ __launch_bounds__(256) void k_tobf16(const float* __restrict__ in, u16* __restrict__ o, int n4) {
  int stride = gridDim.x * 256;
  for (int i = blockIdx.x * 256 + threadIdx.x; i < n4; i += stride) {
    float4 v = *(const float4*)(in + (size_t)i * 4);
    u16x4 u;
    u[0] = bf16r(v.x); u[1] = bf16r(v.y); u[2] = bf16r(v.z); u[3] = bf16r(v.w);
    *(u16x4*)(o + (size_t)i * 4) = u;
  }
}

// Wc1 [256,128] f32 -> Wt [128,256] bf16 (transposed so B-fragments are contiguous in k)
__global__ __launch_bounds__(256) void k_prep_wt(const float* __restrict__ Wc1, u16* __restrict__ Wt) {
  int tid = blockIdx.x * 256 + threadIdx.x;  // 32768
  int o = tid >> 8, k = tid & 255;
  Wt[o * 256 + k] = bf16r(Wc1[k * 128 + o]);
}

// ---------------- fused edge classifier (bf16 MFMA) ----------------
// out[e] = Wc2 . relu([zu[row_t[e]]; zm[col_t[e]]] @ Wc1 + bc1) + bc2
// Block: 256 thr = 4 waves; 128 edges/block (32 per wave = 2 m-tiles of 16).
// Zs: [128 edges][256 k] bf16 = 64KB LDS, XOR-swizzled (byte ^= (row&7)<<4).
__global__ __launch_bounds__(256) void k_classifier_mfma(
    const u16* __restrict__ zub, const u16* __restrict__ zmb,
    const int* __restrict__ row_t, const int* __restrict__ col_t,
    const u16* __restrict__ Wt, const float* __restrict__ bc1,
    const float* __restrict__ Wc2, const float* __restrict__ bc2,
    float* __restrict__ out) {
  __shared__ u16 Zs[128 * 256];  // 64KB
  int tid = threadIdx.x;
  int e0 = blockIdx.x * 128;
  // stage: 4096 chunks of 16B (128 edges x 2 halves x 16 chunks)
  #pragma unroll
  for (int it = 0; it < 16; ++it) {
    int tau = it * 256 + tid;
    int el = tau >> 5, half = (tau >> 4) & 1, c = tau & 15;
    int e = e0 + el; if (e > ETV - 1) e = ETV - 1;
    const u16* src = half ? (zmb + (size_t)col_t[e] * 128) : (zub + (size_t)row_t[e] * 128);
    s16x8 v = *(const s16x8*)(src + c * 8);
    int byt = (el * 512 + half * 256 + c * 16) ^ ((el & 7) << 4);
    *(s16x8*)((char*)Zs + byt) = v;
  }
  __syncthreads();
  int l = tid & 63, wv = tid >> 6;
  int lg = l >> 4, lr = l & 15;
  // A fragments: a[mt][ks] -> edges (wv*32 + mt*16 + lr), k = ks*32 + lg*8 ..+7
  s16x8 a[2][8];
  #pragma unroll
  for (int mt = 0; mt < 2; ++mt) {
    int el = wv * 32 + mt * 16 + lr;
    int rb = el * 512, sw = (el & 7) << 4;
    #pragma unroll
    for (int ks = 0; ks < 8; ++ks)
      a[mt][ks] = *(const s16x8*)((const char*)Zs + ((rb + ks * 64 + lg * 16) ^ sw));
  }
  f32x4 acc[2][8];
  #pragma unroll
  for (int mt = 0; mt < 2; ++mt)
    #pragma unroll
    for (int ct = 0; ct < 8; ++ct) acc[mt][ct] = (f32x4){0.f, 0.f, 0.f, 0.f};
  #pragma unroll
  for (int ct = 0; ct < 8; ++ct) {
    int o = ct * 16 + lr;
    const u16* wp = Wt + (size_t)o * 256 + lg * 8;
    s16x8 b[8];
    #pragma unroll
    for (int ks = 0; ks < 8; ++ks) b[ks] = *(const s16x8*)(wp + ks * 32);
    #pragma unroll
    for (int ks = 0; ks < 8; ++ks) {
      acc[0][ct] = __builtin_amdgcn_mfma_f32_16x16x32_bf16(a[0][ks], b[ks], acc[0][ct], 0, 0, 0);
      acc[1][ct] = __builtin_amdgcn_mfma_f32_16x16x32_bf16(a[1][ks], b[ks], acc[1][ct], 0, 0, 0);
    }
  }
  // epilogue: h = relu(acc + bc1[o]); p = sum_o h*Wc2[o]; reduce over lr (o-dim)
  float bc2v = bc2[0];
  float b1v[8], w2v[8];
  #pragma unroll
  for (int ct = 0; ct < 8; ++ct) { int o = ct * 16 + lr; b1v[ct] = bc1[o]; w2v[ct] = Wc2[o]; }
  #pragma unroll
  for (int mt = 0; mt < 2; ++mt) {
    float p[4] = {0.f, 0.f, 0.f, 0.f};
    #pragma unroll
    for (int ct = 0; ct < 8; ++ct)
      #pragma unroll
      for (int r = 0; r < 4; ++r) {
        float h = acc[mt][ct][r] + b1v[ct];
        h = h > 0.f ? h : 0.f;
        p[r] += h * w2v[ct];
      }
    #pragma unroll
    for (int r = 0; r < 4; ++r)
      #pragma unroll
      for (int d = 1; d < 16; d <<= 1) p[r] += __shfl_xor(p[r], d);
    if (lr == 0) {
      int e = e0 + wv * 32 + mt * 16 + lg * 4;
      if (e < ETV)
        *(float4*)(out + e) = make_float4(p[0] + bc2v, p[1] + bc2v, p[2] + bc2v, p[3] + bc2v);
    }
  }
}

extern "C" void kernel_launch(void* const* d_in, const int* in_sizes, int n_in,
                              void* d_out, int out_size, void* d_ws, size_t ws_size,
                              hipStream_t stream) {
  const float* x_user  = (const float*)d_in[0];
  const float* x_merch = (const float*)d_in[1];
  const int* row_um = (const int*)d_in[2]; const int* col_um = (const int*)d_in[3];
  const int* row_mu = (const int*)d_in[4]; const int* col_mu = (const int*)d_in[5];
  const int* row_t  = (const int*)d_in[6]; const int* col_t  = (const int*)d_in[7];
  const float* W1l_um = (const float*)d_in[8];  const float* W1r_um = (const float*)d_in[9];  const float* b1_um = (const float*)d_in[10];
  const float* W1l_mu = (const float*)d_in[11]; const float* W1r_mu = (const float*)d_in[12]; const float* b1_mu = (const float*)d_in[13];
  const float* W2l_um = (const float*)d_in[14]; const float* W2r_um = (const float*)d_in[15]; const float* b2_um = (const float*)d_in[16];
  const float* W2l_mu = (const float*)d_in[17]; const float* W2r_mu = (const float*)d_in[18]; const float* b2_mu = (const float*)d_in[19];
  const float* Wc1 = (const float*)d_in[20]; const float* bc1 = (const float*)d_in[21];
  const float* Wc2 = (const float*)d_in[22]; const float* bc2 = (const float*)d_in[23];
  float* out = (float*)d_out;

  char* ws = (char*)d_ws;
  size_t p = 0;
  auto alloc = [&](size_t bytes) -> char* {
    char* r = ws + p;
    p = (p + bytes + 255) & ~(size_t)255;
    return r;
  };
  int* off_um = (int*)alloc((size_t)(NMV + 1) * 4);
  int* off_mu = (int*)alloc((size_t)(NUV + 1) * 4);
  int* cur_um = (int*)alloc((size_t)NMV * 4);
  int* cur_mu = (int*)alloc((size_t)NUV * 4);
  size_t zero_end = p;
  int* srow_um = (int*)alloc((size_t)NEV * 4);
  int* srow_mu = (int*)alloc((size_t)NEV * 4);
  float* agg_m = (float*)alloc((size_t)NMV * 128 * 4);  // layer1 [NM,64], layer2 [NM,128]; z_m aliases
  float* agg_u = (float*)alloc((size_t)NUV * 128 * 4);  // layer1 [NU,32], layer2 [NU,128]; z_u aliases
  float* h_m = (float*)alloc((size_t)NMV * 128 * 4);
  float* h_u = (float*)alloc((size_t)NUV * 128 * 4);
  u16* Wt = (u16*)alloc((size_t)128 * 256 * 2);
  float* z_m = agg_m;
  float* z_u = agg_u;
  // bf16 z copies alias dead h buffers (h_* last read by the layer-2 GEMMs)
  u16* zub = (u16*)h_u;
  u16* zmb = (u16*)h_m;
  if (p > ws_size) return;  // workspace too small: fail loudly via absmax

  hipMemsetAsync(d_ws, 0, zero_end, stream);
  // CSR for both edge types (reused by layer 1 and layer 2)
  k_hist<<<1024, 256, 0, stream>>>(col_um, off_um, NEV);
  k_hist<<<1024, 256, 0, stream>>>(col_mu, off_mu, NEV);
  k_scan2<<<2, 1024, 0, stream>>>(off_um, NMV, off_mu, NUV);
  k_scatter<<<1024, 256, 0, stream>>>(col_um, row_um, off_um, cur_um, srow_um, NEV);
  k_scatter<<<1024, 256, 0, stream>>>(col_mu, row_mu, off_mu, cur_mu, srow_mu, NEV);
  // layer 1
  k_agg64<<<(NMV + 3) / 4, 256, 0, stream>>>(off_um, srow_um, x_user, agg_m, NMV);
  k_gemm_dual<64, 32, true><<<NMV / 32, 256, 0, stream>>>(agg_m, x_merch, W1l_um, W1r_um, b1_um, h_m, NMV);
  k_agg32<<<(NUV + 3) / 4, 256, 0, stream>>>(off_mu, srow_mu, x_merch, agg_u, NUV);
  k_gemm_dual<32, 64, true><<<NUV / 32, 256, 0, stream>>>(agg_u, x_user, W1l_mu, W1r_mu, b1_mu, h_u, NUV);
  // layer 2 (z aliases agg: safe, each tile reads its rows before writing them)
  k_agg128<<<(NMV + 3) / 4, 256, 0, stream>>>(off_um, srow_um, h_u, agg_m, NMV);
  k_gemm_dual<128, 128, false><<<NMV / 32, 256, 0, stream>>>(agg_m, h_m, W2l_um, W2r_um, b2_um, z_m, NMV);
  k_agg128<<<(NUV + 3) / 4, 256, 0, stream>>>(off_mu, srow_mu, h_m, agg_u, NUV);
  k_gemm_dual<128, 128, false><<<NUV / 32, 256, 0, stream>>>(agg_u, h_u, W2l_mu, W2r_mu, b2_mu, z_u, NUV);
  // classifier prep (bf16) + fused MFMA classifier
  k_tobf16<<<2048, 256, 0, stream>>>(z_u, zub, NUV * 128 / 4);
  k_tobf16<<<512, 256, 0, stream>>>(z_m, zmb, NMV * 128 / 4);
  k_prep_wt<<<128, 256, 0, stream>>>(Wc1, Wt);
  k_classifier_mfma<<<(ETV + 127) / 128, 256, 0, stream>>>(zub, zmb, row_t, col_t, Wt, bc1, Wc2, bc2, out);
}

// Round 3
// 718.356 us; speedup vs baseline: 1.9290x; 1.4056x over previous
//
#include <hip/hip_runtime.h>
#include <hip/hip_bf16.h>

// Hetero-SAGE: CSR segment-mean aggregation + bf16-MFMA GEMMs + fused edge MLP.
#define NUV 100000
#define NMV 20000
#define NEV 1000000
#define ETV 500000

typedef unsigned short u16;
typedef unsigned int u32;
typedef __attribute__((ext_vector_type(8))) short s16x8;
typedef __attribute__((ext_vector_type(4))) float f32x4;
typedef __attribute__((ext_vector_type(4))) unsigned short u16x4;

__device__ inline u16 bf16r(float f) {  // RTNE float->bf16
  u32 b = __builtin_bit_cast(u32, f);
  u32 r = b + 0x7fffu + ((b >> 16) & 1u);
  return (u16)(r >> 16);
}
__device__ inline float bflo(u32 v) { return __builtin_bit_cast(float, v << 16); }
__device__ inline float bfhi(u32 v) { return __builtin_bit_cast(float, v & 0xffff0000u); }

#define GLOAD_LDS16(src, dst) \
  __builtin_amdgcn_global_load_lds((const __attribute__((address_space(1))) void*)(src), \
                                   (__attribute__((address_space(3))) void*)(dst), 16, 0, 0)

// ---------------- CSR construction ----------------
__global__ __launch_bounds__(256) void k_hist(const int* __restrict__ col, int* __restrict__ off, int n) {
  int stride = gridDim.x * blockDim.x;
  for (int i = blockIdx.x * blockDim.x + threadIdx.x; i < n; i += stride)
    atomicAdd(&off[col[i] + 1], 1);
}

__global__ __launch_bounds__(1024) void k_scan2(int* off_a, int na, int* off_b, int nb) {
  int* off = blockIdx.x ? off_b : off_a;
  int n    = blockIdx.x ? nb    : na;
  __shared__ int wsum[16];
  __shared__ int carry;
  int tid = threadIdx.x, lane = tid & 63, w = tid >> 6;
  if (tid == 0) carry = 0;
  __syncthreads();
  for (int base = 1; base <= n; base += 1024) {
    int i = base + tid;
    int v = (i <= n) ? off[i] : 0;
    int s = v;
    #pragma unroll
    for (int d = 1; d < 64; d <<= 1) { int t = __shfl_up(s, d); if (lane >= d) s += t; }
    if (lane == 63) wsum[w] = s;
    __syncthreads();
    if (w == 0 && lane < 16) {
      int ws_ = wsum[lane];
      #pragma unroll
      for (int d = 1; d < 16; d <<= 1) { int t = __shfl_up(ws_, d); if (lane >= d) ws_ += t; }
      wsum[lane] = ws_;
    }
    __syncthreads();
    int incl = s + (w ? wsum[w - 1] : 0) + carry;
    if (i <= n) off[i] = incl;
    __syncthreads();
    if (tid == 1023) carry = incl;
    __syncthreads();
  }
}

__global__ __launch_bounds__(256) void k_scatter(const int* __restrict__ col, const int* __restrict__ row,
                                                 const int* __restrict__ off, int* __restrict__ cur,
                                                 int* __restrict__ srow, int n) {
  int stride = gridDim.x * blockDim.x;
  for (int i = blockIdx.x * blockDim.x + threadIdx.x; i < n; i += stride) {
    int c = col[i];
    int p = atomicAdd(&cur[c], 1);
    srow[off[c] + p] = row[i];
  }
}

// ---------------- layer-1 segment-mean (fp32 gather, fp32 out) ----------------
__global__ __launch_bounds__(256) void k_agg64(const int* __restrict__ off, const int* __restrict__ srow,
                                               const float* __restrict__ xs, float* __restrict__ agg, int ndst) {
  int wid = (blockIdx.x * 256 + threadIdx.x) >> 6;
  int lane = threadIdx.x & 63;
  if (wid >= ndst) return;
  int s = off[wid], t = off[wid + 1];
  float a0 = 0.f, a1 = 0.f, a2 = 0.f, a3 = 0.f;
  int j = s;
  for (; j + 4 <= t; j += 4) {
    int r0 = srow[j], r1 = srow[j + 1], r2 = srow[j + 2], r3 = srow[j + 3];
    a0 += xs[(size_t)r0 * 64 + lane];
    a1 += xs[(size_t)r1 * 64 + lane];
    a2 += xs[(size_t)r2 * 64 + lane];
    a3 += xs[(size_t)r3 * 64 + lane];
  }
  for (; j < t; ++j) a0 += xs[(size_t)srow[j] * 64 + lane];
  float acc = (a0 + a1) + (a2 + a3);
  agg[(size_t)wid * 64 + lane] = acc / (float)max(t - s, 1);
}

__global__ __launch_bounds__(256) void k_agg32(const int* __restrict__ off, const int* __restrict__ srow,
                                               const float* __restrict__ xs, float* __restrict__ agg, int ndst) {
  int wid = (blockIdx.x * 256 + threadIdx.x) >> 6;
  int lane = threadIdx.x & 63;
  if (wid >= ndst) return;
  int s = off[wid], t = off[wid + 1];
  int half = lane >> 5, f = lane & 31;
  float a0 = 0.f, a1 = 0.f;
  int j = s + half;
  for (; j + 4 <= t; j += 4) {
    int r0 = srow[j], r1 = srow[j + 2];
    a0 += xs[(size_t)r0 * 32 + f];
    a1 += xs[(size_t)r1 * 32 + f];
  }
  for (; j < t; j += 2) a0 += xs[(size_t)srow[j] * 32 + f];
  float acc = a0 + a1;
  acc += __shfl_xor(acc, 32);
  if (half == 0) agg[(size_t)wid * 32 + f] = acc / (float)max(t - s, 1);
}

// ---------------- layer-2 segment-mean (bf16 gather, fp32 accum, bf16 out) ----------------
__global__ __launch_bounds__(256) void k_agg128b(const int* __restrict__ off, const int* __restrict__ srow,
                                                 const u16* __restrict__ hb, u16* __restrict__ aggb, int ndst) {
  int wid = (blockIdx.x * 256 + threadIdx.x) >> 6;
  int lane = threadIdx.x & 63;
  if (wid >= ndst) return;
  int s = off[wid], t = off[wid + 1];
  const u32* x = (const u32*)hb;  // [row][64] packed bf16x2
  float a0x = 0, a0y = 0, a1x = 0, a1y = 0, a2x = 0, a2y = 0, a3x = 0, a3y = 0;
  int j = s;
  for (; j + 4 <= t; j += 4) {
    int r0 = srow[j], r1 = srow[j + 1], r2 = srow[j + 2], r3 = srow[j + 3];
    u32 v0 = x[(size_t)r0 * 64 + lane];
    u32 v1 = x[(size_t)r1 * 64 + lane];
    u32 v2 = x[(size_t)r2 * 64 + lane];
    u32 v3 = x[(size_t)r3 * 64 + lane];
    a0x += bflo(v0); a0y += bfhi(v0);
    a1x += bflo(v1); a1y += bfhi(v1);
    a2x += bflo(v2); a2y += bfhi(v2);
    a3x += bflo(v3); a3y += bfhi(v3);
  }
  for (; j < t; ++j) {
    u32 v = x[(size_t)srow[j] * 64 + lane];
    a0x += bflo(v); a0y += bfhi(v);
  }
  float ax = (a0x + a1x) + (a2x + a3x);
  float ay = (a0y + a1y) + (a2y + a3y);
  float inv = 1.f / (float)max(t - s, 1);
  u32 o = (u32)bf16r(ax * inv) | ((u32)bf16r(ay * inv) << 16);
  ((u32*)aggb)[(size_t)wid * 64 + lane] = o;
}

// ---------------- layer-1 dual GEMM (fp32 in, bf16 out) ----------------
template <int KA, int KB>
__global__ __launch_bounds__(256) void k_gemm_dual(const float* __restrict__ A, const float* __restrict__ B,
                                                   const float* __restrict__ Wa, const float* __restrict__ Wb,
                                                   const float* __restrict__ bias, u16* __restrict__ outb, int nd) {
  __shared__ float At[KA * 32];
  __shared__ float Bt[KB * 32];
  int tid = threadIdx.x;
  int m0 = blockIdx.x * 32;
  {
    int m = tid & 31, kq = tid >> 5;
    const float* Ar = A + (size_t)(m0 + m) * KA;
    for (int k0 = kq * 4; k0 < KA; k0 += 32) {
      float4 v = *(const float4*)(Ar + k0);
      At[(k0 + 0) * 32 + m] = v.x; At[(k0 + 1) * 32 + m] = v.y;
      At[(k0 + 2) * 32 + m] = v.z; At[(k0 + 3) * 32 + m] = v.w;
    }
    const float* Br = B + (size_t)(m0 + m) * KB;
    for (int k0 = kq * 4; k0 < KB; k0 += 32) {
      float4 v = *(const float4*)(Br + k0);
      Bt[(k0 + 0) * 32 + m] = v.x; Bt[(k0 + 1) * 32 + m] = v.y;
      Bt[(k0 + 2) * 32 + m] = v.z; Bt[(k0 + 3) * 32 + m] = v.w;
    }
  }
  __syncthreads();
  int tx = tid & 31, ty = tid >> 5;
  float acc[4][4] = {};
  #pragma unroll 4
  for (int k = 0; k < KA; ++k) {
    float4 wv = *(const float4*)(Wa + k * 128 + tx * 4);
    float4 av = *(const float4*)(&At[k * 32 + ty * 4]);
    float am[4] = {av.x, av.y, av.z, av.w};
    float wo[4] = {wv.x, wv.y, wv.z, wv.w};
    #pragma unroll
    for (int mi = 0; mi < 4; ++mi)
      #pragma unroll
      for (int oi = 0; oi < 4; ++oi) acc[mi][oi] += am[mi] * wo[oi];
  }
  #pragma unroll 4
  for (int k = 0; k < KB; ++k) {
    float4 wv = *(const float4*)(Wb + k * 128 + tx * 4);
    float4 av = *(const float4*)(&Bt[k * 32 + ty * 4]);
    float am[4] = {av.x, av.y, av.z, av.w};
    float wo[4] = {wv.x, wv.y, wv.z, wv.w};
    #pragma unroll
    for (int mi = 0; mi < 4; ++mi)
      #pragma unroll
      for (int oi = 0; oi < 4; ++oi) acc[mi][oi] += am[mi] * wo[oi];
  }
  float4 bv = *(const float4*)(bias + tx * 4);
  float bb[4] = {bv.x, bv.y, bv.z, bv.w};
  #pragma unroll
  for (int mi = 0; mi < 4; ++mi) {
    u16x4 o;
    #pragma unroll
    for (int oi = 0; oi < 4; ++oi) {
      float v = acc[mi][oi] + bb[oi];
      v = v > 0.f ? v : 0.f;  // layer-1 relu
      o[oi] = bf16r(v);
    }
    *(u16x4*)(outb + (size_t)(m0 + ty * 4 + mi) * 128 + tx * 4) = o;
  }
}

// ---------------- weight prep: transpose + bf16 ----------------
__global__ __launch_bounds__(256) void k_prep_w(const float* __restrict__ W2l_um, const float* __restrict__ W2r_um,
                                                const float* __restrict__ W2l_mu, const float* __restrict__ W2r_mu,
                                                const float* __restrict__ Wc1,
                                                u16* __restrict__ Wt2l_um, u16* __restrict__ Wt2r_um,
                                                u16* __restrict__ Wt2l_mu, u16* __restrict__ Wt2r_mu,
                                                u16* __restrict__ Wtc) {
  int tid = blockIdx.x * 256 + threadIdx.x;
  if (tid < 65536) {
    int which = tid >> 14, r = tid & 16383;
    int o = r >> 7, k = r & 127;
    const float* src = which == 0 ? W2l_um : which == 1 ? W2r_um : which == 2 ? W2l_mu : W2r_mu;
    u16* dst = which == 0 ? Wt2l_um : which == 1 ? Wt2r_um : which == 2 ? Wt2l_mu : Wt2r_mu;
    dst[o * 128 + k] = bf16r(src[k * 128 + o]);
  } else if (tid < 98304) {
    int r = tid - 65536;
    int o = r >> 8, k = r & 255;
    Wtc[o * 256 + k] = bf16r(Wc1[k * 128 + o]);
  }
}

// ---------------- layer-2 GEMM (bf16 MFMA): zb = aggb@W2l + hb@W2r + bias ----------------
// 64 rows/block, Zs[64][256] bf16 = 32KB (XOR-swizzled via pre-swizzled global src).
// o-split: wave wv computes cols [wv*32, wv*32+32) for all 64 rows.
__global__ __launch_bounds__(256, 4) void k_gemm2_mfma(
    const u16* __restrict__ aggb, const u16* __restrict__ hb,
    const u16* __restrict__ Wtl, const u16* __restrict__ Wtr,
    const float* __restrict__ bias, u16* __restrict__ zb, int nd) {
  __shared__ u16 Zs[64 * 256];  // 32KB
  int tid = threadIdx.x;
  int r0 = blockIdx.x * 64;
  {
    int half = (tid >> 4) & 1;
    const u16* tab = half ? hb : aggb;
    #pragma unroll
    for (int it = 0; it < 8; ++it) {
      int q = tid + it * 256;
      int rl = q >> 5;
      int cc = (q & 15) ^ (rl & 7);
      int r = r0 + rl; r = r < nd ? r : nd - 1;
      const u16* src = tab + (size_t)r * 128 + cc * 8;
      u16* dst = Zs + (tid >> 6) * 512 + it * 2048;
      GLOAD_LDS16(src, dst);
    }
  }
  __syncthreads();
  int l = tid & 63, wv = tid >> 6;
  int lg = l >> 4, lr = l & 15;
  f32x4 acc[4][2];
  #pragma unroll
  for (int mt = 0; mt < 4; ++mt)
    #pragma unroll
    for (int c = 0; c < 2; ++c) acc[mt][c] = (f32x4){0.f, 0.f, 0.f, 0.f};
  #pragma unroll
  for (int cti = 0; cti < 2; ++cti) {
    int o = (wv * 2 + cti) * 16 + lr;
    const u16* wpl = Wtl + (size_t)o * 128 + lg * 8;
    const u16* wpr = Wtr + (size_t)o * 128 + lg * 8;
    s16x8 b[8];
    #pragma unroll
    for (int ks = 0; ks < 4; ++ks) b[ks] = *(const s16x8*)(wpl + ks * 32);
    #pragma unroll
    for (int ks = 0; ks < 4; ++ks) b[ks + 4] = *(const s16x8*)(wpr + ks * 32);
    #pragma unroll
    for (int mt = 0; mt < 4; ++mt) {
      int rl = mt * 16 + lr;
      int rb = rl * 512, sw = (rl & 7) << 4;
      #pragma unroll
      for (int ks = 0; ks < 8; ++ks) {
        s16x8 a = *(const s16x8*)((const char*)Zs + ((rb + ks * 64 + lg * 16) ^ sw));
        acc[mt][cti] = __builtin_amdgcn_mfma_f32_16x16x32_bf16(a, b[ks], acc[mt][cti], 0, 0, 0);
      }
    }
  }
  float bv[2];
  #pragma unroll
  for (int cti = 0; cti < 2; ++cti) bv[cti] = bias[(wv * 2 + cti) * 16 + lr];
  #pragma unroll
  for (int mt = 0; mt < 4; ++mt)
    #pragma unroll
    for (int cti = 0; cti < 2; ++cti) {
      int o = (wv * 2 + cti) * 16 + lr;
      #pragma unroll
      for (int rg = 0; rg < 4; ++rg) {
        int r = r0 + mt * 16 + lg * 4 + rg;
        if (r < nd) zb[(size_t)r * 128 + o] = bf16r(acc[mt][cti][rg] + bv[cti]);
      }
    }
}

// ---------------- fused edge classifier (bf16 MFMA, o-split) ----------------
__global__ __launch_bounds__(256, 4) void k_classifier_mfma(
    const u16* __restrict__ zub, const u16* __restrict__ zmb,
    const int* __restrict__ row_t, const int* __restrict__ col_t,
    const u16* __restrict__ Wtc, const float* __restrict__ bc1,
    const float* __restrict__ Wc2, const float* __restrict__ bc2,
    float* __restrict__ out) {
  __shared__ u16 Zs[64 * 256];   // 32KB
  __shared__ float part[4][64];  // 1KB cross-wave partials
  int tid = threadIdx.x;
  int e0 = blockIdx.x * 64;
  {
    int half = (tid >> 4) & 1;
    const int* idxp = half ? col_t : row_t;
    const u16* tab = half ? zmb : zub;
    #pragma unroll
    for (int it = 0; it < 8; ++it) {
      int q = tid + it * 256;
      int el = q >> 5;
      int cc = (q & 15) ^ (el & 7);
      int e = e0 + el; e = e < ETV ? e : ETV - 1;
      int idx = idxp[e];
      const u16* src = tab + (size_t)idx * 128 + cc * 8;
      u16* dst = Zs + (tid >> 6) * 512 + it * 2048;
      GLOAD_LDS16(src, dst);
    }
  }
  __syncthreads();
  int l = tid & 63, wv = tid >> 6;
  int lg = l >> 4, lr = l & 15;
  f32x4 acc[4][2];
  #pragma unroll
  for (int mt = 0; mt < 4; ++mt)
    #pragma unroll
    for (int c = 0; c < 2; ++c) acc[mt][c] = (f32x4){0.f, 0.f, 0.f, 0.f};
  #pragma unroll
  for (int cti = 0; cti < 2; ++cti) {
    int o = (wv * 2 + cti) * 16 + lr;
    const u16* wp = Wtc + (size_t)o * 256 + lg * 8;
    s16x8 b[8];
    #pragma unroll
    for (int ks = 0; ks < 8; ++ks) b[ks] = *(const s16x8*)(wp + ks * 32);
    #pragma unroll
    for (int mt = 0; mt < 4; ++mt) {
      int el = mt * 16 + lr;
      int rb = el * 512, sw = (el & 7) << 4;
      #pragma unroll
      for (int ks = 0; ks < 8; ++ks) {
        s16x8 a = *(const s16x8*)((const char*)Zs + ((rb + ks * 64 + lg * 16) ^ sw));
        acc[mt][cti] = __builtin_amdgcn_mfma_f32_16x16x32_bf16(a, b[ks], acc[mt][cti], 0, 0, 0);
      }
    }
  }
  float b1v[2], w2v[2];
  #pragma unroll
  for (int cti = 0; cti < 2; ++cti) {
    int o = (wv * 2 + cti) * 16 + lr;
    b1v[cti] = bc1[o];
    w2v[cti] = Wc2[o];
  }
  #pragma unroll
  for (int mt = 0; mt < 4; ++mt) {
    float pr[4] = {0.f, 0.f, 0.f, 0.f};
    #pragma unroll
    for (int cti = 0; cti < 2; ++cti)
      #pragma unroll
      for (int rg = 0; rg < 4; ++rg) {
        float h = acc[mt][cti][rg] + b1v[cti];
        h = h > 0.f ? h : 0.f;
        pr[rg] += h * w2v[cti];
      }
    #pragma unroll
    for (int rg = 0; rg < 4; ++rg)
      #pragma unroll
      for (int d = 1; d < 16; d <<= 1) pr[rg] += __shfl_xor(pr[rg], d);
    if (lr == 0) {
      #pragma unroll
      for (int rg = 0; rg < 4; ++rg) part[wv][mt * 16 + lg * 4 + rg] = pr[rg];
    }
  }
  __syncthreads();
  if (tid < 64) {
    int e = e0 + tid;
    if (e < ETV)
      out[e] = part[0][tid] + part[1][tid] + part[2][tid] + part[3][tid] + bc2[0];
  }
}

extern "C" void kernel_launch(void* const* d_in, const int* in_sizes, int n_in,
                              void* d_out, int out_size, void* d_ws, size_t ws_size,
                              hipStream_t stream) {
  const float* x_user  = (const float*)d_in[0];
  const float* x_merch = (const float*)d_in[1];
  const int* row_um = (const int*)d_in[2]; const int* col_um = (const int*)d_in[3];
  const int* row_mu = (const int*)d_in[4]; const int* col_mu = (const int*)d_in[5];
  const int* row_t  = (const int*)d_in[6]; const int* col_t  = (const int*)d_in[7];
  const float* W1l_um = (const float*)d_in[8];  const float* W1r_um = (const float*)d_in[9];  const float* b1_um = (const float*)d_in[10];
  const float* W1l_mu = (const float*)d_in[11]; const float* W1r_mu = (const float*)d_in[12]; const float* b1_mu = (const float*)d_in[13];
  const float* W2l_um = (const float*)d_in[14]; const float* W2r_um = (const float*)d_in[15]; const float* b2_um = (const float*)d_in[16];
  const float* W2l_mu = (const float*)d_in[17]; const float* W2r_mu = (const float*)d_in[18]; const float* b2_mu = (const float*)d_in[19];
  const float* Wc1 = (const float*)d_in[20]; const float* bc1 = (const float*)d_in[21];
  const float* Wc2 = (const float*)d_in[22]; const float* bc2 = (const float*)d_in[23];
  float* out = (float*)d_out;

  char* ws = (char*)d_ws;
  size_t p = 0;
  auto alloc = [&](size_t bytes) -> char* {
    char* r = ws + p;
    p = (p + bytes + 255) & ~(size_t)255;
    return r;
  };
  int* off_um = (int*)alloc((size_t)(NMV + 1) * 4);
  int* off_mu = (int*)alloc((size_t)(NUV + 1) * 4);
  int* cur_um = (int*)alloc((size_t)NMV * 4);
  int* cur_mu = (int*)alloc((size_t)NUV * 4);
  size_t zero_end = p;
  int* srow_um = (int*)alloc((size_t)NEV * 4);
  int* srow_mu = (int*)alloc((size_t)NEV * 4);
  float* agg_m = (float*)alloc((size_t)NMV * 64 * 4);    // layer1 merchant agg (fp32, 64 feats)
  float* agg_u = (float*)alloc((size_t)NUV * 32 * 4);    // layer1 user agg (fp32, 32 feats)
  u16* h_m   = (u16*)alloc((size_t)NMV * 128 * 2);       // bf16 hidden
  u16* h_u   = (u16*)alloc((size_t)NUV * 128 * 2);
  u16* aggb_m = (u16*)alloc((size_t)NMV * 128 * 2);      // layer2 agg (bf16)
  u16* aggb_u = (u16*)alloc((size_t)NUV * 128 * 2);
  u16* zmb   = (u16*)alloc((size_t)NMV * 128 * 2);       // bf16 z
  u16* zub   = (u16*)alloc((size_t)NUV * 128 * 2);
  u16* Wt2l_um = (u16*)alloc((size_t)128 * 128 * 2);
  u16* Wt2r_um = (u16*)alloc((size_t)128 * 128 * 2);
  u16* Wt2l_mu = (u16*)alloc((size_t)128 * 128 * 2);
  u16* Wt2r_mu = (u16*)alloc((size_t)128 * 128 * 2);
  u16* Wtc     = (u16*)alloc((size_t)128 * 256 * 2);
  if (p > ws_size) return;  // workspace too small: fail loudly via absmax

  hipMemsetAsync(d_ws, 0, zero_end, stream);
  k_prep_w<<<384, 256, 0, stream>>>(W2l_um, W2r_um, W2l_mu, W2r_mu, Wc1,
                                    Wt2l_um, Wt2r_um, Wt2l_mu, Wt2r_mu, Wtc);
  // CSR for both edge types (reused by layer 1 and layer 2)
  k_hist<<<1024, 256, 0, stream>>>(col_um, off_um, NEV);
  k_hist<<<1024, 256, 0, stream>>>(col_mu, off_mu, NEV);
  k_scan2<<<2, 1024, 0, stream>>>(off_um, NMV, off_mu, NUV);
  k_scatter<<<1024, 256, 0, stream>>>(col_um, row_um, off_um, cur_um, srow_um, NEV);
  k_scatter<<<1024, 256, 0, stream>>>(col_mu, row_mu, off_mu, cur_mu, srow_mu, NEV);
  // layer 1 (fp32 in, bf16 h out)
  k_agg64<<<(NMV + 3) / 4, 256, 0, stream>>>(off_um, srow_um, x_user, agg_m, NMV);
  k_gemm_dual<64, 32><<<NMV / 32, 256, 0, stream>>>(agg_m, x_merch, W1l_um, W1r_um, b1_um, h_m, NMV);
  k_agg32<<<(NUV + 3) / 4, 256, 0, stream>>>(off_mu, srow_mu, x_merch, agg_u, NUV);
  k_gemm_dual<32, 64><<<NUV / 32, 256, 0, stream>>>(agg_u, x_user, W1l_mu, W1r_mu, b1_mu, h_u, NUV);
  // layer 2 (bf16 gather -> bf16 MFMA GEMM -> bf16 z)
  k_agg128b<<<(NMV + 3) / 4, 256, 0, stream>>>(off_um, srow_um, h_u, aggb_m, NMV);
  k_gemm2_mfma<<<(NMV + 63) / 64, 256, 0, stream>>>(aggb_m, h_m, Wt2l_um, Wt2r_um, b2_um, zmb, NMV);
  k_agg128b<<<(NUV + 3) / 4, 256, 0, stream>>>(off_mu, srow_mu, h_m, aggb_u, NUV);
  k_gemm2_mfma<<<(NUV + 63) / 64, 256, 0, stream>>>(aggb_u, h_u, Wt2l_mu, Wt2r_mu, b2_mu, zub, NUV);
  // fused edge classifier
  k_classifier_mfma<<<(ETV + 63) / 64, 256, 0, stream>>>(zub, zmb, row_t, col_t, Wtc, bc1, Wc2, bc2, out);
}

// Round 4
// 670.518 us; speedup vs baseline: 2.0666x; 1.0713x over previous
//
#include <hip/hip_runtime.h>
#include <hip/hip_bf16.h>

// Hetero-SAGE: CSR segment-mean aggregation + bf16-MFMA GEMMs + fused edge MLP.
#define NUV 100000
#define NMV 20000
#define NEV 1000000
#define ETV 500000

typedef unsigned short u16;
typedef unsigned int u32;
typedef __attribute__((ext_vector_type(8))) short s16x8;
typedef __attribute__((ext_vector_type(4))) float f32x4;
typedef __attribute__((ext_vector_type(4))) unsigned short u16x4;

__device__ inline u16 bf16r(float f) {  // RTNE float->bf16
  u32 b = __builtin_bit_cast(u32, f);
  u32 r = b + 0x7fffu + ((b >> 16) & 1u);
  return (u16)(r >> 16);
}
__device__ inline float bflo(u32 v) { return __builtin_bit_cast(float, v << 16); }
__device__ inline float bfhi(u32 v) { return __builtin_bit_cast(float, v & 0xffff0000u); }

#define GLOAD_LDS16(src, dst) \
  __builtin_amdgcn_global_load_lds((const __attribute__((address_space(1))) void*)(src), \
                                   (__attribute__((address_space(3))) void*)(dst), 16, 0, 0)

// ---------------- CSR construction ----------------
__global__ __launch_bounds__(256) void k_hist(const int* __restrict__ col, int* __restrict__ off, int n) {
  int stride = gridDim.x * blockDim.x;
  for (int i = blockIdx.x * blockDim.x + threadIdx.x; i < n; i += stride)
    atomicAdd(&off[col[i] + 1], 1);
}

__global__ __launch_bounds__(1024) void k_scan2(int* off_a, int na, int* off_b, int nb) {
  int* off = blockIdx.x ? off_b : off_a;
  int n    = blockIdx.x ? nb    : na;
  __shared__ int wsum[16];
  __shared__ int carry;
  int tid = threadIdx.x, lane = tid & 63, w = tid >> 6;
  if (tid == 0) carry = 0;
  __syncthreads();
  for (int base = 1; base <= n; base += 1024) {
    int i = base + tid;
    int v = (i <= n) ? off[i] : 0;
    int s = v;
    #pragma unroll
    for (int d = 1; d < 64; d <<= 1) { int t = __shfl_up(s, d); if (lane >= d) s += t; }
    if (lane == 63) wsum[w] = s;
    __syncthreads();
    if (w == 0 && lane < 16) {
      int ws_ = wsum[lane];
      #pragma unroll
      for (int d = 1; d < 16; d <<= 1) { int t = __shfl_up(ws_, d); if (lane >= d) ws_ += t; }
      wsum[lane] = ws_;
    }
    __syncthreads();
    int incl = s + (w ? wsum[w - 1] : 0) + carry;
    if (i <= n) off[i] = incl;
    __syncthreads();
    if (tid == 1023) carry = incl;
    __syncthreads();
  }
}

__global__ __launch_bounds__(256) void k_scatter(const int* __restrict__ col, const int* __restrict__ row,
                                                 const int* __restrict__ off, int* __restrict__ cur,
                                                 int* __restrict__ srow, int n) {
  int stride = gridDim.x * blockDim.x;
  for (int i = blockIdx.x * blockDim.x + threadIdx.x; i < n; i += stride) {
    int c = col[i];
    int p = atomicAdd(&cur[c], 1);
    srow[off[c] + p] = row[i];
  }
}

// ---------------- layer-1 segment-mean (fp32 gather, fp32 out, 8-deep ILP) ----------------
__global__ __launch_bounds__(256) void k_agg64(const int* __restrict__ off, const int* __restrict__ srow,
                                               const float* __restrict__ xs, float* __restrict__ agg, int ndst) {
  int wid = (blockIdx.x * 256 + threadIdx.x) >> 6;
  int lane = threadIdx.x & 63;
  if (wid >= ndst) return;
  int s = off[wid], t = off[wid + 1];
  float a[8] = {};
  int j = s;
  for (; j + 8 <= t; j += 8) {
    int r[8];
    #pragma unroll
    for (int q = 0; q < 8; ++q) r[q] = srow[j + q];
    #pragma unroll
    for (int q = 0; q < 8; ++q) a[q] += xs[(size_t)r[q] * 64 + lane];
  }
  for (; j < t; ++j) a[0] += xs[(size_t)srow[j] * 64 + lane];
  float acc = ((a[0] + a[1]) + (a[2] + a[3])) + ((a[4] + a[5]) + (a[6] + a[7]));
  agg[(size_t)wid * 64 + lane] = acc / (float)max(t - s, 1);
}

__global__ __launch_bounds__(256) void k_agg32(const int* __restrict__ off, const int* __restrict__ srow,
                                               const float* __restrict__ xs, float* __restrict__ agg, int ndst) {
  int wid = (blockIdx.x * 256 + threadIdx.x) >> 6;
  int lane = threadIdx.x & 63;
  if (wid >= ndst) return;
  int s = off[wid], t = off[wid + 1];
  int half = lane >> 5, f = lane & 31;
  float a[4] = {};
  int j = s + half;
  for (; j + 8 <= t; j += 8) {
    int r[4];
    #pragma unroll
    for (int q = 0; q < 4; ++q) r[q] = srow[j + 2 * q];
    #pragma unroll
    for (int q = 0; q < 4; ++q) a[q] += xs[(size_t)r[q] * 32 + f];
  }
  for (; j < t; j += 2) a[0] += xs[(size_t)srow[j] * 32 + f];
  float acc = (a[0] + a[1]) + (a[2] + a[3]);
  acc += __shfl_xor(acc, 32);
  if (half == 0) agg[(size_t)wid * 32 + f] = acc / (float)max(t - s, 1);
}

// ---------------- layer-2 segment-mean (bf16 gather, fp32 accum, bf16 out, 8-deep ILP) ----------------
__global__ __launch_bounds__(256) void k_agg128b(const int* __restrict__ off, const int* __restrict__ srow,
                                                 const u16* __restrict__ hb, u16* __restrict__ aggb, int ndst) {
  int wid = (blockIdx.x * 256 + threadIdx.x) >> 6;
  int lane = threadIdx.x & 63;
  if (wid >= ndst) return;
  int s = off[wid], t = off[wid + 1];
  const u32* x = (const u32*)hb;  // [row][64] packed bf16x2
  float ax[4] = {}, ay[4] = {};
  int j = s;
  for (; j + 8 <= t; j += 8) {
    int r[8];
    #pragma unroll
    for (int q = 0; q < 8; ++q) r[q] = srow[j + q];
    u32 v[8];
    #pragma unroll
    for (int q = 0; q < 8; ++q) v[q] = x[(size_t)r[q] * 64 + lane];
    #pragma unroll
    for (int q = 0; q < 8; ++q) { ax[q & 3] += bflo(v[q]); ay[q & 3] += bfhi(v[q]); }
  }
  for (; j < t; ++j) {
    u32 v = x[(size_t)srow[j] * 64 + lane];
    ax[0] += bflo(v); ay[0] += bfhi(v);
  }
  float sx = (ax[0] + ax[1]) + (ax[2] + ax[3]);
  float sy = (ay[0] + ay[1]) + (ay[2] + ay[3]);
  float inv = 1.f / (float)max(t - s, 1);
  u32 o = (u32)bf16r(sx * inv) | ((u32)bf16r(sy * inv) << 16);
  ((u32*)aggb)[(size_t)wid * 64 + lane] = o;
}

// ---------------- layer-1 dual GEMM (fp32 in, bf16 out) ----------------
template <int KA, int KB>
__global__ __launch_bounds__(256) void k_gemm_dual(const float* __restrict__ A, const float* __restrict__ B,
                                                   const float* __restrict__ Wa, const float* __restrict__ Wb,
                                                   const float* __restrict__ bias, u16* __restrict__ outb, int nd) {
  __shared__ float At[KA * 32];
  __shared__ float Bt[KB * 32];
  int tid = threadIdx.x;
  int m0 = blockIdx.x * 32;
  {
    int m = tid & 31, kq = tid >> 5;
    const float* Ar = A + (size_t)(m0 + m) * KA;
    for (int k0 = kq * 4; k0 < KA; k0 += 32) {
      float4 v = *(const float4*)(Ar + k0);
      At[(k0 + 0) * 32 + m] = v.x; At[(k0 + 1) * 32 + m] = v.y;
      At[(k0 + 2) * 32 + m] = v.z; At[(k0 + 3) * 32 + m] = v.w;
    }
    const float* Br = B + (size_t)(m0 + m) * KB;
    for (int k0 = kq * 4; k0 < KB; k0 += 32) {
      float4 v = *(const float4*)(Br + k0);
      Bt[(k0 + 0) * 32 + m] = v.x; Bt[(k0 + 1) * 32 + m] = v.y;
      Bt[(k0 + 2) * 32 + m] = v.z; Bt[(k0 + 3) * 32 + m] = v.w;
    }
  }
  __syncthreads();
  int tx = tid & 31, ty = tid >> 5;
  float acc[4][4] = {};
  #pragma unroll 4
  for (int k = 0; k < KA; ++k) {
    float4 wv = *(const float4*)(Wa + k * 128 + tx * 4);
    float4 av = *(const float4*)(&At[k * 32 + ty * 4]);
    float am[4] = {av.x, av.y, av.z, av.w};
    float wo[4] = {wv.x, wv.y, wv.z, wv.w};
    #pragma unroll
    for (int mi = 0; mi < 4; ++mi)
      #pragma unroll
      for (int oi = 0; oi < 4; ++oi) acc[mi][oi] += am[mi] * wo[oi];
  }
  #pragma unroll 4
  for (int k = 0; k < KB; ++k) {
    float4 wv = *(const float4*)(Wb + k * 128 + tx * 4);
    float4 av = *(const float4*)(&Bt[k * 32 + ty * 4]);
    float am[4] = {av.x, av.y, av.z, av.w};
    float wo[4] = {wv.x, wv.y, wv.z, wv.w};
    #pragma unroll
    for (int mi = 0; mi < 4; ++mi)
      #pragma unroll
      for (int oi = 0; oi < 4; ++oi) acc[mi][oi] += am[mi] * wo[oi];
  }
  float4 bv = *(const float4*)(bias + tx * 4);
  float bb[4] = {bv.x, bv.y, bv.z, bv.w};
  #pragma unroll
  for (int mi = 0; mi < 4; ++mi) {
    u16x4 o;
    #pragma unroll
    for (int oi = 0; oi < 4; ++oi) {
      float v = acc[mi][oi] + bb[oi];
      v = v > 0.f ? v : 0.f;  // layer-1 relu
      o[oi] = bf16r(v);
    }
    *(u16x4*)(outb + (size_t)(m0 + ty * 4 + mi) * 128 + tx * 4) = o;
  }
}

// ---------------- weight prep: transpose + bf16 ----------------
__global__ __launch_bounds__(256) void k_prep_w(const float* __restrict__ W2l_um, const float* __restrict__ W2r_um,
                                                const float* __restrict__ W2l_mu, const float* __restrict__ W2r_mu,
                                                const float* __restrict__ Wc1,
                                                u16* __restrict__ Wt2l_um, u16* __restrict__ Wt2r_um,
                                                u16* __restrict__ Wt2l_mu, u16* __restrict__ Wt2r_mu,
                                                u16* __restrict__ Wtc) {
  int tid = blockIdx.x * 256 + threadIdx.x;
  if (tid < 65536) {
    int which = tid >> 14, r = tid & 16383;
    int o = r >> 7, k = r & 127;
    const float* src = which == 0 ? W2l_um : which == 1 ? W2r_um : which == 2 ? W2l_mu : W2r_mu;
    u16* dst = which == 0 ? Wt2l_um : which == 1 ? Wt2r_um : which == 2 ? Wt2l_mu : Wt2r_mu;
    dst[o * 128 + k] = bf16r(src[k * 128 + o]);
  } else if (tid < 98304) {
    int r = tid - 65536;
    int o = r >> 8, k = r & 255;
    Wtc[o * 256 + k] = bf16r(Wc1[k * 128 + o]);
  }
}

// ---------------- layer-2 GEMM (bf16 MFMA): zb = aggb@W2l + hb@W2r + bias ----------------
// 64 rows/block, Zs[64][256] bf16 = 32KB (XOR-swizzled via pre-swizzled global src).
// o-split: wave wv computes cols [wv*32, wv*32+32) for all 64 rows.
__global__ __launch_bounds__(256) void k_gemm2_mfma(
    const u16* __restrict__ aggb, const u16* __restrict__ hb,
    const u16* __restrict__ Wtl, const u16* __restrict__ Wtr,
    const float* __restrict__ bias, u16* __restrict__ zb, int nd) {
  __shared__ u16 Zs[64 * 256];  // 32KB
  int tid = threadIdx.x;
  int r0 = blockIdx.x * 64;
  {
    int half = (tid >> 4) & 1;
    const u16* tab = half ? hb : aggb;
    #pragma unroll
    for (int it = 0; it < 8; ++it) {
      int q = tid + it * 256;
      int rl = q >> 5;
      int cc = (q & 15) ^ (rl & 7);
      int r = r0 + rl; r = r < nd ? r : nd - 1;
      const u16* src = tab + (size_t)r * 128 + cc * 8;
      u16* dst = Zs + (tid >> 6) * 512 + it * 2048;
      GLOAD_LDS16(src, dst);
    }
  }
  __syncthreads();
  int l = tid & 63, wv = tid >> 6;
  int lg = l >> 4, lr = l & 15;
  f32x4 acc[4][2];
  #pragma unroll
  for (int mt = 0; mt < 4; ++mt)
    #pragma unroll
    for (int c = 0; c < 2; ++c) acc[mt][c] = (f32x4){0.f, 0.f, 0.f, 0.f};
  #pragma unroll
  for (int cti = 0; cti < 2; ++cti) {
    int o = (wv * 2 + cti) * 16 + lr;
    const u16* wpl = Wtl + (size_t)o * 128 + lg * 8;
    const u16* wpr = Wtr + (size_t)o * 128 + lg * 8;
    s16x8 b[8];
    #pragma unroll
    for (int ks = 0; ks < 4; ++ks) b[ks] = *(const s16x8*)(wpl + ks * 32);
    #pragma unroll
    for (int ks = 0; ks < 4; ++ks) b[ks + 4] = *(const s16x8*)(wpr + ks * 32);
    #pragma unroll
    for (int mt = 0; mt < 4; ++mt) {
      int rl = mt * 16 + lr;
      int rb = rl * 512, sw = (rl & 7) << 4;
      #pragma unroll
      for (int ks = 0; ks < 8; ++ks) {
        s16x8 a = *(const s16x8*)((const char*)Zs + ((rb + ks * 64 + lg * 16) ^ sw));
        acc[mt][cti] = __builtin_amdgcn_mfma_f32_16x16x32_bf16(a, b[ks], acc[mt][cti], 0, 0, 0);
      }
    }
  }
  float bv[2];
  #pragma unroll
  for (int cti = 0; cti < 2; ++cti) bv[cti] = bias[(wv * 2 + cti) * 16 + lr];
  #pragma unroll
  for (int mt = 0; mt < 4; ++mt)
    #pragma unroll
    for (int cti = 0; cti < 2; ++cti) {
      int o = (wv * 2 + cti) * 16 + lr;
      #pragma unroll
      for (int rg = 0; rg < 4; ++rg) {
        int r = r0 + mt * 16 + lg * 4 + rg;
        if (r < nd) zb[(size_t)r * 128 + o] = bf16r(acc[mt][cti][rg] + bv[cti]);
      }
    }
}

// ---------------- fused edge classifier (bf16 MFMA, o-split) ----------------
__global__ __launch_bounds__(256) void k_classifier_mfma(
    const u16* __restrict__ zub, const u16* __restrict__ zmb,
    const int* __restrict__ row_t, const int* __restrict__ col_t,
    const u16* __restrict__ Wtc, const float* __restrict__ bc1,
    const float* __restrict__ Wc2, const float* __restrict__ bc2,
    float* __restrict__ out) {
  __shared__ u16 Zs[64 * 256];   // 32KB
  __shared__ float part[4][64];  // 1KB cross-wave partials
  int tid = threadIdx.x;
  int e0 = blockIdx.x * 64;
  {
    int half = (tid >> 4) & 1;
    const int* idxp = half ? col_t : row_t;
    const u16* tab = half ? zmb : zub;
    #pragma unroll
    for (int it = 0; it < 8; ++it) {
      int q = tid + it * 256;
      int el = q >> 5;
      int cc = (q & 15) ^ (el & 7);
      int e = e0 + el; e = e < ETV ? e : ETV - 1;
      int idx = idxp[e];
      const u16* src = tab + (size_t)idx * 128 + cc * 8;
      u16* dst = Zs + (tid >> 6) * 512 + it * 2048;
      GLOAD_LDS16(src, dst);
    }
  }
  __syncthreads();
  int l = tid & 63, wv = tid >> 6;
  int lg = l >> 4, lr = l & 15;
  f32x4 acc[4][2];
  #pragma unroll
  for (int mt = 0; mt < 4; ++mt)
    #pragma unroll
    for (int c = 0; c < 2; ++c) acc[mt][c] = (f32x4){0.f, 0.f, 0.f, 0.f};
  #pragma unroll
  for (int cti = 0; cti < 2; ++cti) {
    int o = (wv * 2 + cti) * 16 + lr;
    const u16* wp = Wtc + (size_t)o * 256 + lg * 8;
    s16x8 b[8];
    #pragma unroll
    for (int ks = 0; ks < 8; ++ks) b[ks] = *(const s16x8*)(wp + ks * 32);
    #pragma unroll
    for (int mt = 0; mt < 4; ++mt) {
      int el = mt * 16 + lr;
      int rb = el * 512, sw = (el & 7) << 4;
      #pragma unroll
      for (int ks = 0; ks < 8; ++ks) {
        s16x8 a = *(const s16x8*)((const char*)Zs + ((rb + ks * 64 + lg * 16) ^ sw));
        acc[mt][cti] = __builtin_amdgcn_mfma_f32_16x16x32_bf16(a, b[ks], acc[mt][cti], 0, 0, 0);
      }
    }
  }
  float b1v[2], w2v[2];
  #pragma unroll
  for (int cti = 0; cti < 2; ++cti) {
    int o = (wv * 2 + cti) * 16 + lr;
    b1v[cti] = bc1[o];
    w2v[cti] = Wc2[o];
  }
  #pragma unroll
  for (int mt = 0; mt < 4; ++mt) {
    float pr[4] = {0.f, 0.f, 0.f, 0.f};
    #pragma unroll
    for (int cti = 0; cti < 2; ++cti)
      #pragma unroll
      for (int rg = 0; rg < 4; ++rg) {
        float h = acc[mt][cti][rg] + b1v[cti];
        h = h > 0.f ? h : 0.f;
        pr[rg] += h * w2v[cti];
      }
    #pragma unroll
    for (int rg = 0; rg < 4; ++rg)
      #pragma unroll
      for (int d = 1; d < 16; d <<= 1) pr[rg] += __shfl_xor(pr[rg], d);
    if (lr == 0) {
      #pragma unroll
      for (int rg = 0; rg < 4; ++rg) part[wv][mt * 16 + lg * 4 + rg] = pr[rg];
    }
  }
  __syncthreads();
  if (tid < 64) {
    int e = e0 + tid;
    if (e < ETV)
      out[e] = part[0][tid] + part[1][tid] + part[2][tid] + part[3][tid] + bc2[0];
  }
}

extern "C" void kernel_launch(void* const* d_in, const int* in_sizes, int n_in,
                              void* d_out, int out_size, void* d_ws, size_t ws_size,
                              hipStream_t stream) {
  const float* x_user  = (const float*)d_in[0];
  const float* x_merch = (const float*)d_in[1];
  const int* row_um = (const int*)d_in[2]; const int* col_um = (const int*)d_in[3];
  const int* row_mu = (const int*)d_in[4]; const int* col_mu = (const int*)d_in[5];
  const int* row_t  = (const int*)d_in[6]; const int* col_t  = (const int*)d_in[7];
  const float* W1l_um = (const float*)d_in[8];  const float* W1r_um = (const float*)d_in[9];  const float* b1_um = (const float*)d_in[10];
  const float* W1l_mu = (const float*)d_in[11]; const float* W1r_mu = (const float*)d_in[12]; const float* b1_mu = (const float*)d_in[13];
  const float* W2l_um = (const float*)d_in[14]; const float* W2r_um = (const float*)d_in[15]; const float* b2_um = (const float*)d_in[16];
  const float* W2l_mu = (const float*)d_in[17]; const float* W2r_mu = (const float*)d_in[18]; const float* b2_mu = (const float*)d_in[19];
  const float* Wc1 = (const float*)d_in[20]; const float* bc1 = (const float*)d_in[21];
  const float* Wc2 = (const float*)d_in[22]; const float* bc2 = (const float*)d_in[23];
  float* out = (float*)d_out;

  char* ws = (char*)d_ws;
  size_t p = 0;
  auto alloc = [&](size_t bytes) -> char* {
    char* r = ws + p;
    p = (p + bytes + 255) & ~(size_t)255;
    return r;
  };
  int* off_um = (int*)alloc((size_t)(NMV + 1) * 4);
  int* off_mu = (int*)alloc((size_t)(NUV + 1) * 4);
  int* cur_um = (int*)alloc((size_t)NMV * 4);
  int* cur_mu = (int*)alloc((size_t)NUV * 4);
  size_t zero_end = p;
  int* srow_um = (int*)alloc((size_t)NEV * 4);
  int* srow_mu = (int*)alloc((size_t)NEV * 4);
  float* agg_m = (float*)alloc((size_t)NMV * 64 * 4);    // layer1 merchant agg (fp32, 64 feats)
  float* agg_u = (float*)alloc((size_t)NUV * 32 * 4);    // layer1 user agg (fp32, 32 feats)
  u16* h_m   = (u16*)alloc((size_t)NMV * 128 * 2);       // bf16 hidden
  u16* h_u   = (u16*)alloc((size_t)NUV * 128 * 2);
  u16* aggb_m = (u16*)alloc((size_t)NMV * 128 * 2);      // layer2 agg (bf16)
  u16* aggb_u = (u16*)alloc((size_t)NUV * 128 * 2);
  u16* zmb   = (u16*)alloc((size_t)NMV * 128 * 2);       // bf16 z
  u16* zub   = (u16*)alloc((size_t)NUV * 128 * 2);
  u16* Wt2l_um = (u16*)alloc((size_t)128 * 128 * 2);
  u16* Wt2r_um = (u16*)alloc((size_t)128 * 128 * 2);
  u16* Wt2l_mu = (u16*)alloc((size_t)128 * 128 * 2);
  u16* Wt2r_mu = (u16*)alloc((size_t)128 * 128 * 2);
  u16* Wtc     = (u16*)alloc((size_t)128 * 256 * 2);
  if (p > ws_size) return;  // workspace too small: fail loudly via absmax

  hipMemsetAsync(d_ws, 0, zero_end, stream);
  k_prep_w<<<384, 256, 0, stream>>>(W2l_um, W2r_um, W2l_mu, W2r_mu, Wc1,
                                    Wt2l_um, Wt2r_um, Wt2l_mu, Wt2r_mu, Wtc);
  // CSR for both edge types (reused by layer 1 and layer 2)
  k_hist<<<1024, 256, 0, stream>>>(col_um, off_um, NEV);
  k_hist<<<1024, 256, 0, stream>>>(col_mu, off_mu, NEV);
  k_scan2<<<2, 1024, 0, stream>>>(off_um, NMV, off_mu, NUV);
  k_scatter<<<1024, 256, 0, stream>>>(col_um, row_um, off_um, cur_um, srow_um, NEV);
  k_scatter<<<1024, 256, 0, stream>>>(col_mu, row_mu, off_mu, cur_mu, srow_mu, NEV);
  // layer 1 (fp32 in, bf16 h out)
  k_agg64<<<(NMV + 3) / 4, 256, 0, stream>>>(off_um, srow_um, x_user, agg_m, NMV);
  k_gemm_dual<64, 32><<<NMV / 32, 256, 0, stream>>>(agg_m, x_merch, W1l_um, W1r_um, b1_um, h_m, NMV);
  k_agg32<<<(NUV + 3) / 4, 256, 0, stream>>>(off_mu, srow_mu, x_merch, agg_u, NUV);
  k_gemm_dual<32, 64><<<NUV / 32, 256, 0, stream>>>(agg_u, x_user, W1l_mu, W1r_mu, b1_mu, h_u, NUV);
  // layer 2 (bf16 gather -> bf16 MFMA GEMM -> bf16 z)
  k_agg128b<<<(NMV + 3) / 4, 256, 0, stream>>>(off_um, srow_um, h_u, aggb_m, NMV);
  k_gemm2_mfma<<<(NMV + 63) / 64, 256, 0, stream>>>(aggb_m, h_m, Wt2l_um, Wt2r_um, b2_um, zmb, NMV);
  k_agg128b<<<(NUV + 3) / 4, 256, 0, stream>>>(off_mu, srow_mu, h_m, aggb_u, NUV);
  k_gemm2_mfma<<<(NUV + 63) / 64, 256, 0, stream>>>(aggb_u, h_u, Wt2l_mu, Wt2r_mu, b2_mu, zub, NUV);
  // fused edge classifier
  k_classifier_mfma<<<(ETV + 63) / 64, 256, 0, stream>>>(zub, zmb, row_t, col_t, Wtc, bc1, Wc2, bc2, out);
}

// Round 5
// 615.517 us; speedup vs baseline: 2.2513x; 1.0894x over previous
//
#include <hip/hip_runtime.h>
#include <hip/hip_bf16.h>

// Hetero-SAGE: CSR segment-mean aggregation + bf16-MFMA GEMMs with folded classifier.
// Key identity: layer-2 has no activation, so z@Wc1 folds into the layer-2 GEMM:
//   pu = z_u@Wc1u = agg_u@(W2l_mu@Wc1u) + h_u@(W2r_mu@Wc1u) + b2_mu@Wc1u
// and the edge classifier becomes out[e] = Wc2 . relu(pu[row]+pm[col]) + bc2.
#define NUV 100000
#define NMV 20000
#define NEV 1000000
#define ETV 500000

typedef unsigned short u16;
typedef unsigned int u32;
typedef __attribute__((ext_vector_type(8))) short s16x8;
typedef __attribute__((ext_vector_type(4))) float f32x4;
typedef __attribute__((ext_vector_type(4))) unsigned short u16x4;

__device__ inline u16 bf16r(float f) {  // RTNE float->bf16
  u32 b = __builtin_bit_cast(u32, f);
  u32 r = b + 0x7fffu + ((b >> 16) & 1u);
  return (u16)(r >> 16);
}
__device__ inline float bflo(u32 v) { return __builtin_bit_cast(float, v << 16); }
__device__ inline float bfhi(u32 v) { return __builtin_bit_cast(float, v & 0xffff0000u); }

#define GLOAD_LDS16(src, dst) \
  __builtin_amdgcn_global_load_lds((const __attribute__((address_space(1))) void*)(src), \
                                   (__attribute__((address_space(3))) void*)(dst), 16, 0, 0)

// ---------------- CSR construction ----------------
__global__ __launch_bounds__(256) void k_hist(const int* __restrict__ col, int* __restrict__ off, int n) {
  int stride = gridDim.x * blockDim.x;
  for (int i = blockIdx.x * blockDim.x + threadIdx.x; i < n; i += stride)
    atomicAdd(&off[col[i] + 1], 1);
}

__global__ __launch_bounds__(1024) void k_scan2(int* off_a, int na, int* off_b, int nb) {
  int* off = blockIdx.x ? off_b : off_a;
  int n    = blockIdx.x ? nb    : na;
  __shared__ int wsum[16];
  __shared__ int carry;
  int tid = threadIdx.x, lane = tid & 63, w = tid >> 6;
  if (tid == 0) carry = 0;
  __syncthreads();
  for (int base = 1; base <= n; base += 1024) {
    int i = base + tid;
    int v = (i <= n) ? off[i] : 0;
    int s = v;
    #pragma unroll
    for (int d = 1; d < 64; d <<= 1) { int t = __shfl_up(s, d); if (lane >= d) s += t; }
    if (lane == 63) wsum[w] = s;
    __syncthreads();
    if (w == 0 && lane < 16) {
      int ws_ = wsum[lane];
      #pragma unroll
      for (int d = 1; d < 16; d <<= 1) { int t = __shfl_up(ws_, d); if (lane >= d) ws_ += t; }
      wsum[lane] = ws_;
    }
    __syncthreads();
    int incl = s + (w ? wsum[w - 1] : 0) + carry;
    if (i <= n) off[i] = incl;
    __syncthreads();
    if (tid == 1023) carry = incl;
    __syncthreads();
  }
}

__global__ __launch_bounds__(256) void k_scatter(const int* __restrict__ col, const int* __restrict__ row,
                                                 const int* __restrict__ off, int* __restrict__ cur,
                                                 int* __restrict__ srow, int n) {
  int stride = gridDim.x * blockDim.x;
  for (int i = blockIdx.x * blockDim.x + threadIdx.x; i < n; i += stride) {
    int c = col[i];
    int p = atomicAdd(&cur[c], 1);
    srow[off[c] + p] = row[i];
  }
}

// ---------------- layer-1 segment-mean (fp32 gather, fp32 out, 8-deep ILP) ----------------
__global__ __launch_bounds__(256) void k_agg64(const int* __restrict__ off, const int* __restrict__ srow,
                                               const float* __restrict__ xs, float* __restrict__ agg, int ndst) {
  int wid = (blockIdx.x * 256 + threadIdx.x) >> 6;
  int lane = threadIdx.x & 63;
  if (wid >= ndst) return;
  int s = off[wid], t = off[wid + 1];
  float a[8] = {};
  int j = s;
  for (; j + 8 <= t; j += 8) {
    int r[8];
    #pragma unroll
    for (int q = 0; q < 8; ++q) r[q] = srow[j + q];
    #pragma unroll
    for (int q = 0; q < 8; ++q) a[q] += xs[(size_t)r[q] * 64 + lane];
  }
  for (; j < t; ++j) a[0] += xs[(size_t)srow[j] * 64 + lane];
  float acc = ((a[0] + a[1]) + (a[2] + a[3])) + ((a[4] + a[5]) + (a[6] + a[7]));
  agg[(size_t)wid * 64 + lane] = acc / (float)max(t - s, 1);
}

__global__ __launch_bounds__(256) void k_agg32(const int* __restrict__ off, const int* __restrict__ srow,
                                               const float* __restrict__ xs, float* __restrict__ agg, int ndst) {
  int wid = (blockIdx.x * 256 + threadIdx.x) >> 6;
  int lane = threadIdx.x & 63;
  if (wid >= ndst) return;
  int s = off[wid], t = off[wid + 1];
  int half = lane >> 5, f = lane & 31;
  float a[4] = {};
  int j = s + half;
  for (; j + 8 <= t; j += 8) {
    int r[4];
    #pragma unroll
    for (int q = 0; q < 4; ++q) r[q] = srow[j + 2 * q];
    #pragma unroll
    for (int q = 0; q < 4; ++q) a[q] += xs[(size_t)r[q] * 32 + f];
  }
  for (; j < t; j += 2) a[0] += xs[(size_t)srow[j] * 32 + f];
  float acc = (a[0] + a[1]) + (a[2] + a[3]);
  acc += __shfl_xor(acc, 32);
  if (half == 0) agg[(size_t)wid * 32 + f] = acc / (float)max(t - s, 1);
}

// ---------------- layer-2 segment-mean (bf16 gather, fp32 accum, bf16 out, 8-deep ILP) ----------------
__global__ __launch_bounds__(256) void k_agg128b(const int* __restrict__ off, const int* __restrict__ srow,
                                                 const u16* __restrict__ hb, u16* __restrict__ aggb, int ndst) {
  int wid = (blockIdx.x * 256 + threadIdx.x) >> 6;
  int lane = threadIdx.x & 63;
  if (wid >= ndst) return;
  int s = off[wid], t = off[wid + 1];
  const u32* x = (const u32*)hb;  // [row][64] packed bf16x2
  float ax[4] = {}, ay[4] = {};
  int j = s;
  for (; j + 8 <= t; j += 8) {
    int r[8];
    #pragma unroll
    for (int q = 0; q < 8; ++q) r[q] = srow[j + q];
    u32 v[8];
    #pragma unroll
    for (int q = 0; q < 8; ++q) v[q] = x[(size_t)r[q] * 64 + lane];
    #pragma unroll
    for (int q = 0; q < 8; ++q) { ax[q & 3] += bflo(v[q]); ay[q & 3] += bfhi(v[q]); }
  }
  for (; j < t; ++j) {
    u32 v = x[(size_t)srow[j] * 64 + lane];
    ax[0] += bflo(v); ay[0] += bfhi(v);
  }
  float sx = (ax[0] + ax[1]) + (ax[2] + ax[3]);
  float sy = (ay[0] + ay[1]) + (ay[2] + ay[3]);
  float inv = 1.f / (float)max(t - s, 1);
  u32 o = (u32)bf16r(sx * inv) | ((u32)bf16r(sy * inv) << 16);
  ((u32*)aggb)[(size_t)wid * 64 + lane] = o;
}

// ---------------- layer-1 dual GEMM (fp32 in, bf16 out) ----------------
template <int KA, int KB>
__global__ __launch_bounds__(256) void k_gemm_dual(const float* __restrict__ A, const float* __restrict__ B,
                                                   const float* __restrict__ Wa, const float* __restrict__ Wb,
                                                   const float* __restrict__ bias, u16* __restrict__ outb, int nd) {
  __shared__ float At[KA * 32];
  __shared__ float Bt[KB * 32];
  int tid = threadIdx.x;
  int m0 = blockIdx.x * 32;
  {
    int m = tid & 31, kq = tid >> 5;
    const float* Ar = A + (size_t)(m0 + m) * KA;
    for (int k0 = kq * 4; k0 < KA; k0 += 32) {
      float4 v = *(const float4*)(Ar + k0);
      At[(k0 + 0) * 32 + m] = v.x; At[(k0 + 1) * 32 + m] = v.y;
      At[(k0 + 2) * 32 + m] = v.z; At[(k0 + 3) * 32 + m] = v.w;
    }
    const float* Br = B + (size_t)(m0 + m) * KB;
    for (int k0 = kq * 4; k0 < KB; k0 += 32) {
      float4 v = *(const float4*)(Br + k0);
      Bt[(k0 + 0) * 32 + m] = v.x; Bt[(k0 + 1) * 32 + m] = v.y;
      Bt[(k0 + 2) * 32 + m] = v.z; Bt[(k0 + 3) * 32 + m] = v.w;
    }
  }
  __syncthreads();
  int tx = tid & 31, ty = tid >> 5;
  float acc[4][4] = {};
  #pragma unroll 4
  for (int k = 0; k < KA; ++k) {
    float4 wv = *(const float4*)(Wa + k * 128 + tx * 4);
    float4 av = *(const float4*)(&At[k * 32 + ty * 4]);
    float am[4] = {av.x, av.y, av.z, av.w};
    float wo[4] = {wv.x, wv.y, wv.z, wv.w};
    #pragma unroll
    for (int mi = 0; mi < 4; ++mi)
      #pragma unroll
      for (int oi = 0; oi < 4; ++oi) acc[mi][oi] += am[mi] * wo[oi];
  }
  #pragma unroll 4
  for (int k = 0; k < KB; ++k) {
    float4 wv = *(const float4*)(Wb + k * 128 + tx * 4);
    float4 av = *(const float4*)(&Bt[k * 32 + ty * 4]);
    float am[4] = {av.x, av.y, av.z, av.w};
    float wo[4] = {wv.x, wv.y, wv.z, wv.w};
    #pragma unroll
    for (int mi = 0; mi < 4; ++mi)
      #pragma unroll
      for (int oi = 0; oi < 4; ++oi) acc[mi][oi] += am[mi] * wo[oi];
  }
  float4 bv = *(const float4*)(bias + tx * 4);
  float bb[4] = {bv.x, bv.y, bv.z, bv.w};
  #pragma unroll
  for (int mi = 0; mi < 4; ++mi) {
    u16x4 o;
    #pragma unroll
    for (int oi = 0; oi < 4; ++oi) {
      float v = acc[mi][oi] + bb[oi];
      v = v > 0.f ? v : 0.f;  // layer-1 relu
      o[oi] = bf16r(v);
    }
    *(u16x4*)(outb + (size_t)(m0 + ty * 4 + mi) * 128 + tx * 4) = o;
  }
}

// ---------------- combined-weight prep: Wt = (W2 @ Wc1half)^T in bf16, plus folded biases ----------------
// mats: 0: W2l_mu@Wc1u  1: W2r_mu@Wc1u  2: W2l_um@Wc1m  3: W2r_um@Wc1m  (u: rows 0..127, m: 128..255)
__global__ __launch_bounds__(256) void k_prep_comb(
    const float* __restrict__ W2l_um, const float* __restrict__ W2r_um,
    const float* __restrict__ W2l_mu, const float* __restrict__ W2r_mu,
    const float* __restrict__ b2_um, const float* __restrict__ b2_mu,
    const float* __restrict__ Wc1, const float* __restrict__ bc1,
    u16* __restrict__ WtA_u, u16* __restrict__ WtB_u,
    u16* __restrict__ WtA_m, u16* __restrict__ WtB_m,
    float* __restrict__ bias_u, float* __restrict__ bias_m) {
  int t = blockIdx.x * 256 + threadIdx.x;
  if (t < 65536) {
    int mat = t >> 14, rem = t & 16383;
    int o = rem >> 7, k = rem & 127;
    const float* W2 = mat == 0 ? W2l_mu : mat == 1 ? W2r_mu : mat == 2 ? W2l_um : W2r_um;
    const float* wc = Wc1 + (mat >= 2 ? 128 * 128 : 0) + o;
    float s = 0.f;
    #pragma unroll 4
    for (int j = 0; j < 128; ++j) s += W2[k * 128 + j] * wc[j * 128];
    u16* dst = mat == 0 ? WtA_u : mat == 1 ? WtB_u : mat == 2 ? WtA_m : WtB_m;
    dst[o * 128 + k] = bf16r(s);
  } else if (t < 65536 + 256) {
    int r = t - 65536;
    int o = r & 127;
    if (r < 128) {
      float s = 0.f;
      for (int j = 0; j < 128; ++j) s += b2_mu[j] * Wc1[j * 128 + o];
      bias_u[o] = s;
    } else {
      float s = bc1[o];  // fold bc1 into merchant-side bias
      for (int j = 0; j < 128; ++j) s += b2_um[j] * Wc1[(128 + j) * 128 + o];
      bias_m[o] = s;
    }
  }
}

// ---------------- layer-2 GEMM (bf16 MFMA): outb = bf16(aggb@Wtl + hb@Wtr + bias) ----------------
// 64 rows/block, Zs[64][256] bf16 = 32KB (XOR-swizzled via pre-swizzled global src).
// o-split: wave wv computes cols [wv*32, wv*32+32) for all 64 rows.
__global__ __launch_bounds__(256) void k_gemm2_mfma(
    const u16* __restrict__ aggb, const u16* __restrict__ hb,
    const u16* __restrict__ Wtl, const u16* __restrict__ Wtr,
    const float* __restrict__ bias, u16* __restrict__ zb, int nd) {
  __shared__ u16 Zs[64 * 256];  // 32KB
  int tid = threadIdx.x;
  int r0 = blockIdx.x * 64;
  {
    int half = (tid >> 4) & 1;
    const u16* tab = half ? hb : aggb;
    #pragma unroll
    for (int it = 0; it < 8; ++it) {
      int q = tid + it * 256;
      int rl = q >> 5;
      int cc = (q & 15) ^ (rl & 7);
      int r = r0 + rl; r = r < nd ? r : nd - 1;
      const u16* src = tab + (size_t)r * 128 + cc * 8;
      u16* dst = Zs + (tid >> 6) * 512 + it * 2048;
      GLOAD_LDS16(src, dst);
    }
  }
  __syncthreads();
  int l = tid & 63, wv = tid >> 6;
  int lg = l >> 4, lr = l & 15;
  f32x4 acc[4][2];
  #pragma unroll
  for (int mt = 0; mt < 4; ++mt)
    #pragma unroll
    for (int c = 0; c < 2; ++c) acc[mt][c] = (f32x4){0.f, 0.f, 0.f, 0.f};
  #pragma unroll
  for (int cti = 0; cti < 2; ++cti) {
    int o = (wv * 2 + cti) * 16 + lr;
    const u16* wpl = Wtl + (size_t)o * 128 + lg * 8;
    const u16* wpr = Wtr + (size_t)o * 128 + lg * 8;
    s16x8 b[8];
    #pragma unroll
    for (int ks = 0; ks < 4; ++ks) b[ks] = *(const s16x8*)(wpl + ks * 32);
    #pragma unroll
    for (int ks = 0; ks < 4; ++ks) b[ks + 4] = *(const s16x8*)(wpr + ks * 32);
    #pragma unroll
    for (int mt = 0; mt < 4; ++mt) {
      int rl = mt * 16 + lr;
      int rb = rl * 512, sw = (rl & 7) << 4;
      #pragma unroll
      for (int ks = 0; ks < 8; ++ks) {
        s16x8 a = *(const s16x8*)((const char*)Zs + ((rb + ks * 64 + lg * 16) ^ sw));
        acc[mt][cti] = __builtin_amdgcn_mfma_f32_16x16x32_bf16(a, b[ks], acc[mt][cti], 0, 0, 0);
      }
    }
  }
  float bv[2];
  #pragma unroll
  for (int cti = 0; cti < 2; ++cti) bv[cti] = bias[(wv * 2 + cti) * 16 + lr];
  #pragma unroll
  for (int mt = 0; mt < 4; ++mt)
    #pragma unroll
    for (int cti = 0; cti < 2; ++cti) {
      int o = (wv * 2 + cti) * 16 + lr;
      #pragma unroll
      for (int rg = 0; rg < 4; ++rg) {
        int r = r0 + mt * 16 + lg * 4 + rg;
        if (r < nd) zb[(size_t)r * 128 + o] = bf16r(acc[mt][cti][rg] + bv[cti]);
      }
    }
}

// ---------------- edge op: out[e] = Wc2 . relu(pu[row_t[e]] + pm[col_t[e]]) + bc2 ----------------
// One wave per edge-iteration (coalesced 256B row reads), 4-edge ILP, LDS-collect for coalesced out.
__global__ __launch_bounds__(256) void k_edge(
    const u32* __restrict__ pu, const u32* __restrict__ pm,
    const int* __restrict__ row_t, const int* __restrict__ col_t,
    const float* __restrict__ Wc2, const float* __restrict__ bc2,
    float* __restrict__ out) {
  __shared__ float res[256];
  int tid = threadIdx.x, l = tid & 63, wv = tid >> 6;
  float w0 = Wc2[2 * l], w1 = Wc2[2 * l + 1];
  int base = blockIdx.x * 256 + wv * 64;
  #pragma unroll 1
  for (int it = 0; it < 64; it += 4) {
    int r[4], c[4];
    #pragma unroll
    for (int q = 0; q < 4; ++q) {
      int e = base + it + q;
      e = e < ETV ? e : ETV - 1;
      r[q] = row_t[e]; c[q] = col_t[e];
    }
    u32 a[4], b[4];
    #pragma unroll
    for (int q = 0; q < 4; ++q) {
      a[q] = pu[(size_t)r[q] * 64 + l];
      b[q] = pm[(size_t)c[q] * 64 + l];
    }
    #pragma unroll
    for (int q = 0; q < 4; ++q) {
      float h0 = bflo(a[q]) + bflo(b[q]);
      float h1 = bfhi(a[q]) + bfhi(b[q]);
      h0 = h0 > 0.f ? h0 : 0.f;
      h1 = h1 > 0.f ? h1 : 0.f;
      float p = h0 * w0 + h1 * w1;
      #pragma unroll
      for (int d = 1; d < 64; d <<= 1) p += __shfl_xor(p, d);
      if (l == 0) res[wv * 64 + it + q] = p;
    }
  }
  __syncthreads();
  int eo = blockIdx.x * 256 + tid;
  if (eo < ETV) out[eo] = res[tid] + bc2[0];
}

extern "C" void kernel_launch(void* const* d_in, const int* in_sizes, int n_in,
                              void* d_out, int out_size, void* d_ws, size_t ws_size,
                              hipStream_t stream) {
  const float* x_user  = (const float*)d_in[0];
  const float* x_merch = (const float*)d_in[1];
  const int* row_um = (const int*)d_in[2]; const int* col_um = (const int*)d_in[3];
  const int* row_mu = (const int*)d_in[4]; const int* col_mu = (const int*)d_in[5];
  const int* row_t  = (const int*)d_in[6]; const int* col_t  = (const int*)d_in[7];
  const float* W1l_um = (const float*)d_in[8];  const float* W1r_um = (const float*)d_in[9];  const float* b1_um = (const float*)d_in[10];
  const float* W1l_mu = (const float*)d_in[11]; const float* W1r_mu = (const float*)d_in[12]; const float* b1_mu = (const float*)d_in[13];
  const float* W2l_um = (const float*)d_in[14]; const float* W2r_um = (const float*)d_in[15]; const float* b2_um = (const float*)d_in[16];
  const float* W2l_mu = (const float*)d_in[17]; const float* W2r_mu = (const float*)d_in[18]; const float* b2_mu = (const float*)d_in[19];
  const float* Wc1 = (const float*)d_in[20]; const float* bc1 = (const float*)d_in[21];
  const float* Wc2 = (const float*)d_in[22]; const float* bc2 = (const float*)d_in[23];
  float* out = (float*)d_out;

  char* ws = (char*)d_ws;
  size_t p = 0;
  auto alloc = [&](size_t bytes) -> char* {
    char* r = ws + p;
    p = (p + bytes + 255) & ~(size_t)255;
    return r;
  };
  int* off_um = (int*)alloc((size_t)(NMV + 1) * 4);
  int* off_mu = (int*)alloc((size_t)(NUV + 1) * 4);
  int* cur_um = (int*)alloc((size_t)NMV * 4);
  int* cur_mu = (int*)alloc((size_t)NUV * 4);
  size_t zero_end = p;
  int* srow_um = (int*)alloc((size_t)NEV * 4);
  int* srow_mu = (int*)alloc((size_t)NEV * 4);
  float* agg_m = (float*)alloc((size_t)NMV * 64 * 4);    // layer1 merchant agg (fp32, 64 feats)
  float* agg_u = (float*)alloc((size_t)NUV * 32 * 4);    // layer1 user agg (fp32, 32 feats)
  u16* h_m   = (u16*)alloc((size_t)NMV * 128 * 2);       // bf16 hidden
  u16* h_u   = (u16*)alloc((size_t)NUV * 128 * 2);
  u16* aggb_m = (u16*)alloc((size_t)NMV * 128 * 2);      // layer2 agg (bf16)
  u16* aggb_u = (u16*)alloc((size_t)NUV * 128 * 2);
  u16* pm_b  = (u16*)alloc((size_t)NMV * 128 * 2);       // folded classifier projections (bf16)
  u16* pu_b  = (u16*)alloc((size_t)NUV * 128 * 2);
  u16* WtA_u = (u16*)alloc((size_t)128 * 128 * 2);
  u16* WtB_u = (u16*)alloc((size_t)128 * 128 * 2);
  u16* WtA_m = (u16*)alloc((size_t)128 * 128 * 2);
  u16* WtB_m = (u16*)alloc((size_t)128 * 128 * 2);
  float* bias_u = (float*)alloc(128 * 4);
  float* bias_m = (float*)alloc(128 * 4);
  if (p > ws_size) return;  // workspace too small: fail loudly via absmax

  hipMemsetAsync(d_ws, 0, zero_end, stream);
  k_prep_comb<<<257, 256, 0, stream>>>(W2l_um, W2r_um, W2l_mu, W2r_mu, b2_um, b2_mu, Wc1, bc1,
                                       WtA_u, WtB_u, WtA_m, WtB_m, bias_u, bias_m);
  // CSR for both edge types (reused by layer 1 and layer 2)
  k_hist<<<1024, 256, 0, stream>>>(col_um, off_um, NEV);
  k_hist<<<1024, 256, 0, stream>>>(col_mu, off_mu, NEV);
  k_scan2<<<2, 1024, 0, stream>>>(off_um, NMV, off_mu, NUV);
  k_scatter<<<1024, 256, 0, stream>>>(col_um, row_um, off_um, cur_um, srow_um, NEV);
  k_scatter<<<1024, 256, 0, stream>>>(col_mu, row_mu, off_mu, cur_mu, srow_mu, NEV);
  // layer 1 (fp32 in, bf16 h out)
  k_agg64<<<(NMV + 3) / 4, 256, 0, stream>>>(off_um, srow_um, x_user, agg_m, NMV);
  k_gemm_dual<64, 32><<<NMV / 32, 256, 0, stream>>>(agg_m, x_merch, W1l_um, W1r_um, b1_um, h_m, NMV);
  k_agg32<<<(NUV + 3) / 4, 256, 0, stream>>>(off_mu, srow_mu, x_merch, agg_u, NUV);
  k_gemm_dual<32, 64><<<NUV / 32, 256, 0, stream>>>(agg_u, x_user, W1l_mu, W1r_mu, b1_mu, h_u, NUV);
  // layer 2 with folded classifier weights -> pu/pm directly (z never materialized)
  k_agg128b<<<(NMV + 3) / 4, 256, 0, stream>>>(off_um, srow_um, h_u, aggb_m, NMV);
  k_gemm2_mfma<<<(NMV + 63) / 64, 256, 0, stream>>>(aggb_m, h_m, WtA_m, WtB_m, bias_m, pm_b, NMV);
  k_agg128b<<<(NUV + 3) / 4, 256, 0, stream>>>(off_mu, srow_mu, h_m, aggb_u, NUV);
  k_gemm2_mfma<<<(NUV + 63) / 64, 256, 0, stream>>>(aggb_u, h_u, WtA_u, WtB_u, bias_u, pu_b, NUV);
  // edge classifier: gather + relu + dot
  k_edge<<<(ETV + 255) / 256, 256, 0, stream>>>((const u32*)pu_b, (const u32*)pm_b,
                                                row_t, col_t, Wc2, bc2, out);
}

// Round 6
// 530.761 us; speedup vs baseline: 2.6108x; 1.1597x over previous
//
#include <hip/hip_runtime.h>
#include <hip/hip_bf16.h>

// Hetero-SAGE: CSR segment-mean aggregation + bf16-MFMA GEMMs with folded classifier.
// Layer-2 has no activation, so z@Wc1 folds into the layer-2 GEMM weights; edge op is
// out[e] = Wc2 . relu(pu[row]+pm[col]) + bc2.
#define NUV 100000
#define NMV 20000
#define NEV 1000000
#define ETV 500000

#define SCHUNK 4096
#define NCHA 5    // ceil(20000/4096)
#define NCHB 25   // ceil(100000/4096)

typedef unsigned short u16;
typedef unsigned int u32;
typedef __attribute__((ext_vector_type(8))) short s16x8;
typedef __attribute__((ext_vector_type(4))) float f32x4;
typedef __attribute__((ext_vector_type(4))) unsigned short u16x4;
typedef __attribute__((ext_vector_type(4))) unsigned int u32x4;

__device__ inline u16 bf16r(float f) {  // RTNE float->bf16
  u32 b = __builtin_bit_cast(u32, f);
  u32 r = b + 0x7fffu + ((b >> 16) & 1u);
  return (u16)(r >> 16);
}
__device__ inline float bflo(u32 v) { return __builtin_bit_cast(float, v << 16); }
__device__ inline float bfhi(u32 v) { return __builtin_bit_cast(float, v & 0xffff0000u); }

#define GLOAD_LDS16(src, dst) \
  __builtin_amdgcn_global_load_lds((const __attribute__((address_space(1))) void*)(src), \
                                   (__attribute__((address_space(3))) void*)(dst), 16, 0, 0)

// ---------------- CSR construction ----------------
__global__ __launch_bounds__(256) void k_hist(const int* __restrict__ col, int* __restrict__ off, int n) {
  int stride = gridDim.x * blockDim.x;
  for (int i = blockIdx.x * blockDim.x + threadIdx.x; i < n; i += stride)
    atomicAdd(&off[col[i] + 1], 1);
}

// ---- multi-block scan: p1 chunk sums, p2 chunk-offset scan, p3 final ----
__global__ __launch_bounds__(1024) void k_scan_p1(const int* __restrict__ offA, int nA,
                                                  const int* __restrict__ offB, int nB,
                                                  int* __restrict__ bsum) {
  int b = blockIdx.x;
  const int* off; int n; int c;
  if (b < NCHA) { off = offA + 1; n = nA; c = b; }
  else          { off = offB + 1; n = nB; c = b - NCHA; }
  __shared__ int wsum[16];
  int tid = threadIdx.x, lane = tid & 63, w = tid >> 6;
  int base = c * SCHUNK + tid * 4;
  int s = 0;
  #pragma unroll
  for (int q = 0; q < 4; ++q) s += (base + q < n) ? off[base + q] : 0;
  #pragma unroll
  for (int d = 1; d < 64; d <<= 1) s += __shfl_xor(s, d);
  if (lane == 0) wsum[w] = s;
  __syncthreads();
  if (tid == 0) {
    int tot = 0;
    #pragma unroll
    for (int i = 0; i < 16; ++i) tot += wsum[i];
    bsum[b] = tot;
  }
}

__global__ __launch_bounds__(64) void k_scan_p2(int* __restrict__ bsum) {
  int lane = threadIdx.x;
  int v = 0;
  if (lane < NCHA) v = bsum[lane];
  else if (lane >= 32 && lane < 32 + NCHB) v = bsum[NCHA + lane - 32];
  int s = v;
  #pragma unroll
  for (int d = 1; d < 32; d <<= 1) { int t = __shfl_up(s, d, 32); if ((lane & 31) >= d) s += t; }
  int ex = s - v;
  if (lane < NCHA) bsum[lane] = ex;
  else if (lane >= 32 && lane < 32 + NCHB) bsum[NCHA + lane - 32] = ex;
}

__global__ __launch_bounds__(1024) void k_scan_p3(int* __restrict__ offA, int nA,
                                                  int* __restrict__ offB, int nB,
                                                  const int* __restrict__ bsum) {
  int b = blockIdx.x;
  int* off; int n; int c;
  if (b < NCHA) { off = offA + 1; n = nA; c = b; }
  else          { off = offB + 1; n = nB; c = b - NCHA; }
  int carry = bsum[b];
  __shared__ int wsum[16];
  int tid = threadIdx.x, lane = tid & 63, w = tid >> 6;
  int base = c * SCHUNK + tid * 4;
  int v[4];
  #pragma unroll
  for (int q = 0; q < 4; ++q) v[q] = (base + q < n) ? off[base + q] : 0;
  int p1 = v[0] + v[1], p2 = p1 + v[2], p3 = p2 + v[3];
  int s = p3, sc = s;
  #pragma unroll
  for (int d = 1; d < 64; d <<= 1) { int t = __shfl_up(sc, d); if (lane >= d) sc += t; }
  if (lane == 63) wsum[w] = sc;
  __syncthreads();
  if (w == 0 && lane < 16) {
    int ws_ = wsum[lane];
    #pragma unroll
    for (int d = 1; d < 16; d <<= 1) { int t = __shfl_up(ws_, d, 16); if (lane >= d) ws_ += t; }
    wsum[lane] = ws_;
  }
  __syncthreads();
  int ex = sc - s + (w ? wsum[w - 1] : 0) + carry;
  if (base + 0 < n) off[base + 0] = ex + v[0];
  if (base + 1 < n) off[base + 1] = ex + p1;
  if (base + 2 < n) off[base + 2] = ex + p2;
  if (base + 3 < n) off[base + 3] = ex + p3;
}

__global__ __launch_bounds__(256) void k_scatter(const int* __restrict__ col, const int* __restrict__ row,
                                                 const int* __restrict__ off, int* __restrict__ cur,
                                                 int* __restrict__ srow, int n) {
  int stride = gridDim.x * blockDim.x;
  for (int i = blockIdx.x * blockDim.x + threadIdx.x; i < n; i += stride) {
    int c = col[i];
    int p = atomicAdd(&cur[c], 1);
    srow[off[c] + p] = row[i];
  }
}

// ---------------- x_user -> bf16 (halves layer-1 gather traffic) ----------------
__global__ __launch_bounds__(256) void k_xub(const float* __restrict__ in, u32* __restrict__ o, int n8) {
  int stride = gridDim.x * 256;
  for (int i = blockIdx.x * 256 + threadIdx.x; i < n8; i += stride) {
    float4 a = *(const float4*)(in + (size_t)i * 8);
    float4 b = *(const float4*)(in + (size_t)i * 8 + 4);
    u32x4 r;
    r[0] = (u32)bf16r(a.x) | ((u32)bf16r(a.y) << 16);
    r[1] = (u32)bf16r(a.z) | ((u32)bf16r(a.w) << 16);
    r[2] = (u32)bf16r(b.x) | ((u32)bf16r(b.y) << 16);
    r[3] = (u32)bf16r(b.z) | ((u32)bf16r(b.w) << 16);
    *(u32x4*)(o + (size_t)i * 4) = r;
  }
}

// ---------------- layer-1 merchant agg (bf16 gather of x_user, fp32 out) ----------------
// half-wave per edge: 32 lanes x u32 (2 feats) = 128B row
__global__ __launch_bounds__(256) void k_agg64b(const int* __restrict__ off, const int* __restrict__ srow,
                                                const u32* __restrict__ xb, float* __restrict__ agg, int ndst) {
  int wid = (blockIdx.x * 256 + threadIdx.x) >> 6;
  int lane = threadIdx.x & 63;
  if (wid >= ndst) return;
  int s = off[wid], t = off[wid + 1];
  int half = lane >> 5, f = lane & 31;
  float ax[4] = {}, ay[4] = {};
  int j = s + half;
  for (; j + 8 <= t; j += 8) {
    int r[4];
    #pragma unroll
    for (int q = 0; q < 4; ++q) r[q] = srow[j + 2 * q];
    u32 v[4];
    #pragma unroll
    for (int q = 0; q < 4; ++q) v[q] = xb[(size_t)r[q] * 32 + f];
    #pragma unroll
    for (int q = 0; q < 4; ++q) { ax[q] += bflo(v[q]); ay[q] += bfhi(v[q]); }
  }
  for (; j < t; j += 2) {
    u32 v = xb[(size_t)srow[j] * 32 + f];
    ax[0] += bflo(v); ay[0] += bfhi(v);
  }
  float sx = (ax[0] + ax[1]) + (ax[2] + ax[3]);
  float sy = (ay[0] + ay[1]) + (ay[2] + ay[3]);
  sx += __shfl_xor(sx, 32);
  sy += __shfl_xor(sy, 32);
  if (half == 0) {
    float inv = 1.f / (float)max(t - s, 1);
    ((float2*)agg)[(size_t)wid * 32 + f] = make_float2(sx * inv, sy * inv);
  }
}

__global__ __launch_bounds__(256) void k_agg32(const int* __restrict__ off, const int* __restrict__ srow,
                                               const float* __restrict__ xs, float* __restrict__ agg, int ndst) {
  int wid = (blockIdx.x * 256 + threadIdx.x) >> 6;
  int lane = threadIdx.x & 63;
  if (wid >= ndst) return;
  int s = off[wid], t = off[wid + 1];
  int half = lane >> 5, f = lane & 31;
  float a[4] = {};
  int j = s + half;
  for (; j + 8 <= t; j += 8) {
    int r[4];
    #pragma unroll
    for (int q = 0; q < 4; ++q) r[q] = srow[j + 2 * q];
    #pragma unroll
    for (int q = 0; q < 4; ++q) a[q] += xs[(size_t)r[q] * 32 + f];
  }
  for (; j < t; j += 2) a[0] += xs[(size_t)srow[j] * 32 + f];
  float acc = (a[0] + a[1]) + (a[2] + a[3]);
  acc += __shfl_xor(acc, 32);
  if (half == 0) agg[(size_t)wid * 32 + f] = acc / (float)max(t - s, 1);
}

// ---------------- layer-2 segment-mean (bf16 gather, fp32 accum, bf16 out, 8-deep ILP) ----------------
__global__ __launch_bounds__(256) void k_agg128b(const int* __restrict__ off, const int* __restrict__ srow,
                                                 const u16* __restrict__ hb, u16* __restrict__ aggb, int ndst) {
  int wid = (blockIdx.x * 256 + threadIdx.x) >> 6;
  int lane = threadIdx.x & 63;
  if (wid >= ndst) return;
  int s = off[wid], t = off[wid + 1];
  const u32* x = (const u32*)hb;  // [row][64] packed bf16x2
  float ax[4] = {}, ay[4] = {};
  int j = s;
  for (; j + 8 <= t; j += 8) {
    int r[8];
    #pragma unroll
    for (int q = 0; q < 8; ++q) r[q] = srow[j + q];
    u32 v[8];
    #pragma unroll
    for (int q = 0; q < 8; ++q) v[q] = x[(size_t)r[q] * 64 + lane];
    #pragma unroll
    for (int q = 0; q < 8; ++q) { ax[q & 3] += bflo(v[q]); ay[q & 3] += bfhi(v[q]); }
  }
  for (; j < t; ++j) {
    u32 v = x[(size_t)srow[j] * 64 + lane];
    ax[0] += bflo(v); ay[0] += bfhi(v);
  }
  float sx = (ax[0] + ax[1]) + (ax[2] + ax[3]);
  float sy = (ay[0] + ay[1]) + (ay[2] + ay[3]);
  float inv = 1.f / (float)max(t - s, 1);
  u32 o = (u32)bf16r(sx * inv) | ((u32)bf16r(sy * inv) << 16);
  ((u32*)aggb)[(size_t)wid * 64 + lane] = o;
}

// ---------------- layer-1 dual GEMM (fp32 in, bf16 out) ----------------
template <int KA, int KB>
__global__ __launch_bounds__(256) void k_gemm_dual(const float* __restrict__ A, const float* __restrict__ B,
                                                   const float* __restrict__ Wa, const float* __restrict__ Wb,
                                                   const float* __restrict__ bias, u16* __restrict__ outb, int nd) {
  __shared__ float At[KA * 32];
  __shared__ float Bt[KB * 32];
  int tid = threadIdx.x;
  int m0 = blockIdx.x * 32;
  {
    int m = tid & 31, kq = tid >> 5;
    const float* Ar = A + (size_t)(m0 + m) * KA;
    for (int k0 = kq * 4; k0 < KA; k0 += 32) {
      float4 v = *(const float4*)(Ar + k0);
      At[(k0 + 0) * 32 + m] = v.x; At[(k0 + 1) * 32 + m] = v.y;
      At[(k0 + 2) * 32 + m] = v.z; At[(k0 + 3) * 32 + m] = v.w;
    }
    const float* Br = B + (size_t)(m0 + m) * KB;
    for (int k0 = kq * 4; k0 < KB; k0 += 32) {
      float4 v = *(const float4*)(Br + k0);
      Bt[(k0 + 0) * 32 + m] = v.x; Bt[(k0 + 1) * 32 + m] = v.y;
      Bt[(k0 + 2) * 32 + m] = v.z; Bt[(k0 + 3) * 32 + m] = v.w;
    }
  }
  __syncthreads();
  int tx = tid & 31, ty = tid >> 5;
  float acc[4][4] = {};
  #pragma unroll 4
  for (int k = 0; k < KA; ++k) {
    float4 wv = *(const float4*)(Wa + k * 128 + tx * 4);
    float4 av = *(const float4*)(&At[k * 32 + ty * 4]);
    float am[4] = {av.x, av.y, av.z, av.w};
    float wo[4] = {wv.x, wv.y, wv.z, wv.w};
    #pragma unroll
    for (int mi = 0; mi < 4; ++mi)
      #pragma unroll
      for (int oi = 0; oi < 4; ++oi) acc[mi][oi] += am[mi] * wo[oi];
  }
  #pragma unroll 4
  for (int k = 0; k < KB; ++k) {
    float4 wv = *(const float4*)(Wb + k * 128 + tx * 4);
    float4 av = *(const float4*)(&Bt[k * 32 + ty * 4]);
    float am[4] = {av.x, av.y, av.z, av.w};
    float wo[4] = {wv.x, wv.y, wv.z, wv.w};
    #pragma unroll
    for (int mi = 0; mi < 4; ++mi)
      #pragma unroll
      for (int oi = 0; oi < 4; ++oi) acc[mi][oi] += am[mi] * wo[oi];
  }
  float4 bv = *(const float4*)(bias + tx * 4);
  float bb[4] = {bv.x, bv.y, bv.z, bv.w};
  #pragma unroll
  for (int mi = 0; mi < 4; ++mi) {
    u16x4 o;
    #pragma unroll
    for (int oi = 0; oi < 4; ++oi) {
      float v = acc[mi][oi] + bb[oi];
      v = v > 0.f ? v : 0.f;  // layer-1 relu
      o[oi] = bf16r(v);
    }
    *(u16x4*)(outb + (size_t)(m0 + ty * 4 + mi) * 128 + tx * 4) = o;
  }
}

// ---------------- combined-weight prep: Wt = (W2 @ Wc1half)^T in bf16, plus folded biases ----------------
__global__ __launch_bounds__(256) void k_prep_comb(
    const float* __restrict__ W2l_um, const float* __restrict__ W2r_um,
    const float* __restrict__ W2l_mu, const float* __restrict__ W2r_mu,
    const float* __restrict__ b2_um, const float* __restrict__ b2_mu,
    const float* __restrict__ Wc1, const float* __restrict__ bc1,
    u16* __restrict__ WtA_u, u16* __restrict__ WtB_u,
    u16* __restrict__ WtA_m, u16* __restrict__ WtB_m,
    float* __restrict__ bias_u, float* __restrict__ bias_m) {
  int t = blockIdx.x * 256 + threadIdx.x;
  if (t < 65536) {
    int mat = t >> 14, rem = t & 16383;
    int o = rem >> 7, k = rem & 127;
    const float* W2 = mat == 0 ? W2l_mu : mat == 1 ? W2r_mu : mat == 2 ? W2l_um : W2r_um;
    const float* wc = Wc1 + (mat >= 2 ? 128 * 128 : 0) + o;
    float s = 0.f;
    #pragma unroll 4
    for (int j = 0; j < 128; ++j) s += W2[k * 128 + j] * wc[j * 128];
    u16* dst = mat == 0 ? WtA_u : mat == 1 ? WtB_u : mat == 2 ? WtA_m : WtB_m;
    dst[o * 128 + k] = bf16r(s);
  } else if (t < 65536 + 256) {
    int r = t - 65536;
    int o = r & 127;
    if (r < 128) {
      float s = 0.f;
      for (int j = 0; j < 128; ++j) s += b2_mu[j] * Wc1[j * 128 + o];
      bias_u[o] = s;
    } else {
      float s = bc1[o];  // fold bc1 into merchant-side bias
      for (int j = 0; j < 128; ++j) s += b2_um[j] * Wc1[(128 + j) * 128 + o];
      bias_m[o] = s;
    }
  }
}

// ---------------- layer-2 GEMM (bf16 MFMA): outb = bf16(aggb@Wtl + hb@Wtr + bias) ----------------
__global__ __launch_bounds__(256) void k_gemm2_mfma(
    const u16* __restrict__ aggb, const u16* __restrict__ hb,
    const u16* __restrict__ Wtl, const u16* __restrict__ Wtr,
    const float* __restrict__ bias, u16* __restrict__ zb, int nd) {
  __shared__ u16 Zs[64 * 256];  // 32KB
  int tid = threadIdx.x;
  int r0 = blockIdx.x * 64;
  {
    int half = (tid >> 4) & 1;
    const u16* tab = half ? hb : aggb;
    #pragma unroll
    for (int it = 0; it < 8; ++it) {
      int q = tid + it * 256;
      int rl = q >> 5;
      int cc = (q & 15) ^ (rl & 7);
      int r = r0 + rl; r = r < nd ? r : nd - 1;
      const u16* src = tab + (size_t)r * 128 + cc * 8;
      u16* dst = Zs + (tid >> 6) * 512 + it * 2048;
      GLOAD_LDS16(src, dst);
    }
  }
  __syncthreads();
  int l = tid & 63, wv = tid >> 6;
  int lg = l >> 4, lr = l & 15;
  f32x4 acc[4][2];
  #pragma unroll
  for (int mt = 0; mt < 4; ++mt)
    #pragma unroll
    for (int c = 0; c < 2; ++c) acc[mt][c] = (f32x4){0.f, 0.f, 0.f, 0.f};
  #pragma unroll
  for (int cti = 0; cti < 2; ++cti) {
    int o = (wv * 2 + cti) * 16 + lr;
    const u16* wpl = Wtl + (size_t)o * 128 + lg * 8;
    const u16* wpr = Wtr + (size_t)o * 128 + lg * 8;
    s16x8 b[8];
    #pragma unroll
    for (int ks = 0; ks < 4; ++ks) b[ks] = *(const s16x8*)(wpl + ks * 32);
    #pragma unroll
    for (int ks = 0; ks < 4; ++ks) b[ks + 4] = *(const s16x8*)(wpr + ks * 32);
    #pragma unroll
    for (int mt = 0; mt < 4; ++mt) {
      int rl = mt * 16 + lr;
      int rb = rl * 512, sw = (rl & 7) << 4;
      #pragma unroll
      for (int ks = 0; ks < 8; ++ks) {
        s16x8 a = *(const s16x8*)((const char*)Zs + ((rb + ks * 64 + lg * 16) ^ sw));
        acc[mt][cti] = __builtin_amdgcn_mfma_f32_16x16x32_bf16(a, b[ks], acc[mt][cti], 0, 0, 0);
      }
    }
  }
  float bv[2];
  #pragma unroll
  for (int cti = 0; cti < 2; ++cti) bv[cti] = bias[(wv * 2 + cti) * 16 + lr];
  #pragma unroll
  for (int mt = 0; mt < 4; ++mt)
    #pragma unroll
    for (int cti = 0; cti < 2; ++cti) {
      int o = (wv * 2 + cti) * 16 + lr;
      #pragma unroll
      for (int rg = 0; rg < 4; ++rg) {
        int r = r0 + mt * 16 + lg * 4 + rg;
        if (r < nd) zb[(size_t)r * 128 + o] = bf16r(acc[mt][cti][rg] + bv[cti]);
      }
    }
}

// ---------------- edge op: out[e] = Wc2 . relu(pu[row_t[e]] + pm[col_t[e]]) + bc2 ----------------
__global__ __launch_bounds__(256) void k_edge(
    const u32* __restrict__ pu, const u32* __restrict__ pm,
    const int* __restrict__ row_t, const int* __restrict__ col_t,
    const float* __restrict__ Wc2, const float* __restrict__ bc2,
    float* __restrict__ out) {
  __shared__ float res[256];
  int tid = threadIdx.x, l = tid & 63, wv = tid >> 6;
  float w0 = Wc2[2 * l], w1 = Wc2[2 * l + 1];
  int base = blockIdx.x * 256 + wv * 64;
  #pragma unroll 1
  for (int it = 0; it < 64; it += 4) {
    int r[4], c[4];
    #pragma unroll
    for (int q = 0; q < 4; ++q) {
      int e = base + it + q;
      e = e < ETV ? e : ETV - 1;
      r[q] = row_t[e]; c[q] = col_t[e];
    }
    u32 a[4], b[4];
    #pragma unroll
    for (int q = 0; q < 4; ++q) {
      a[q] = pu[(size_t)r[q] * 64 + l];
      b[q] = pm[(size_t)c[q] * 64 + l];
    }
    #pragma unroll
    for (int q = 0; q < 4; ++q) {
      float h0 = bflo(a[q]) + bflo(b[q]);
      float h1 = bfhi(a[q]) + bfhi(b[q]);
      h0 = h0 > 0.f ? h0 : 0.f;
      h1 = h1 > 0.f ? h1 : 0.f;
      float p = h0 * w0 + h1 * w1;
      #pragma unroll
      for (int d = 1; d < 64; d <<= 1) p += __shfl_xor(p, d);
      if (l == 0) res[wv * 64 + it + q] = p;
    }
  }
  __syncthreads();
  int eo = blockIdx.x * 256 + tid;
  if (eo < ETV) out[eo] = res[tid] + bc2[0];
}

extern "C" void kernel_launch(void* const* d_in, const int* in_sizes, int n_in,
                              void* d_out, int out_size, void* d_ws, size_t ws_size,
                              hipStream_t stream) {
  const float* x_user  = (const float*)d_in[0];
  const float* x_merch = (const float*)d_in[1];
  const int* row_um = (const int*)d_in[2]; const int* col_um = (const int*)d_in[3];
  const int* row_mu = (const int*)d_in[4]; const int* col_mu = (const int*)d_in[5];
  const int* row_t  = (const int*)d_in[6]; const int* col_t  = (const int*)d_in[7];
  const float* W1l_um = (const float*)d_in[8];  const float* W1r_um = (const float*)d_in[9];  const float* b1_um = (const float*)d_in[10];
  const float* W1l_mu = (const float*)d_in[11]; const float* W1r_mu = (const float*)d_in[12]; const float* b1_mu = (const float*)d_in[13];
  const float* W2l_um = (const float*)d_in[14]; const float* W2r_um = (const float*)d_in[15]; const float* b2_um = (const float*)d_in[16];
  const float* W2l_mu = (const float*)d_in[17]; const float* W2r_mu = (const float*)d_in[18]; const float* b2_mu = (const float*)d_in[19];
  const float* Wc1 = (const float*)d_in[20]; const float* bc1 = (const float*)d_in[21];
  const float* Wc2 = (const float*)d_in[22]; const float* bc2 = (const float*)d_in[23];
  float* out = (float*)d_out;

  char* ws = (char*)d_ws;
  size_t p = 0;
  auto alloc = [&](size_t bytes) -> char* {
    char* r = ws + p;
    p = (p + bytes + 255) & ~(size_t)255;
    return r;
  };
  int* off_um = (int*)alloc((size_t)(NMV + 1) * 4);
  int* off_mu = (int*)alloc((size_t)(NUV + 1) * 4);
  int* cur_um = (int*)alloc((size_t)NMV * 4);
  int* cur_mu = (int*)alloc((size_t)NUV * 4);
  size_t zero_end = p;
  int* bsum = (int*)alloc((size_t)(NCHA + NCHB) * 4);
  int* srow_um = (int*)alloc((size_t)NEV * 4);
  int* srow_mu = (int*)alloc((size_t)NEV * 4);
  u32* xub = (u32*)alloc((size_t)NUV * 32 * 4);          // x_user in bf16 (packed pairs)
  float* agg_m = (float*)alloc((size_t)NMV * 64 * 4);    // layer1 merchant agg (fp32, 64 feats)
  float* agg_u = (float*)alloc((size_t)NUV * 32 * 4);    // layer1 user agg (fp32, 32 feats)
  u16* h_m   = (u16*)alloc((size_t)NMV * 128 * 2);       // bf16 hidden
  u16* h_u   = (u16*)alloc((size_t)NUV * 128 * 2);
  u16* aggb_m = (u16*)alloc((size_t)NMV * 128 * 2);      // layer2 agg (bf16)
  u16* aggb_u = (u16*)alloc((size_t)NUV * 128 * 2);
  u16* pm_b  = (u16*)alloc((size_t)NMV * 128 * 2);       // folded classifier projections (bf16)
  u16* pu_b  = (u16*)alloc((size_t)NUV * 128 * 2);
  u16* WtA_u = (u16*)alloc((size_t)128 * 128 * 2);
  u16* WtB_u = (u16*)alloc((size_t)128 * 128 * 2);
  u16* WtA_m = (u16*)alloc((size_t)128 * 128 * 2);
  u16* WtB_m = (u16*)alloc((size_t)128 * 128 * 2);
  float* bias_u = (float*)alloc(128 * 4);
  float* bias_m = (float*)alloc(128 * 4);
  if (p > ws_size) return;  // workspace too small: fail loudly via absmax

  hipMemsetAsync(d_ws, 0, zero_end, stream);
  k_prep_comb<<<257, 256, 0, stream>>>(W2l_um, W2r_um, W2l_mu, W2r_mu, b2_um, b2_mu, Wc1, bc1,
                                       WtA_u, WtB_u, WtA_m, WtB_m, bias_u, bias_m);
  k_xub<<<1024, 256, 0, stream>>>(x_user, xub, NUV * 64 / 8);
  // CSR for both edge types (reused by layer 1 and layer 2)
  k_hist<<<1024, 256, 0, stream>>>(col_um, off_um, NEV);
  k_hist<<<1024, 256, 0, stream>>>(col_mu, off_mu, NEV);
  k_scan_p1<<<NCHA + NCHB, 1024, 0, stream>>>(off_um, NMV, off_mu, NUV, bsum);
  k_scan_p2<<<1, 64, 0, stream>>>(bsum);
  k_scan_p3<<<NCHA + NCHB, 1024, 0, stream>>>(off_um, NMV, off_mu, NUV, bsum);
  k_scatter<<<1024, 256, 0, stream>>>(col_um, row_um, off_um, cur_um, srow_um, NEV);
  k_scatter<<<1024, 256, 0, stream>>>(col_mu, row_mu, off_mu, cur_mu, srow_mu, NEV);
  // layer 1 (bf16/fp32 in, bf16 h out)
  k_agg64b<<<(NMV + 3) / 4, 256, 0, stream>>>(off_um, srow_um, xub, agg_m, NMV);
  k_gemm_dual<64, 32><<<NMV / 32, 256, 0, stream>>>(agg_m, x_merch, W1l_um, W1r_um, b1_um, h_m, NMV);
  k_agg32<<<(NUV + 3) / 4, 256, 0, stream>>>(off_mu, srow_mu, x_merch, agg_u, NUV);
  k_gemm_dual<32, 64><<<NUV / 32, 256, 0, stream>>>(agg_u, x_user, W1l_mu, W1r_mu, b1_mu, h_u, NUV);
  // layer 2 with folded classifier weights -> pu/pm directly (z never materialized)
  k_agg128b<<<(NMV + 3) / 4, 256, 0, stream>>>(off_um, srow_um, h_u, aggb_m, NMV);
  k_gemm2_mfma<<<(NMV + 63) / 64, 256, 0, stream>>>(aggb_m, h_m, WtA_m, WtB_m, bias_m, pm_b, NMV);
  k_agg128b<<<(NUV + 3) / 4, 256, 0, stream>>>(off_mu, srow_mu, h_m, aggb_u, NUV);
  k_gemm2_mfma<<<(NUV + 63) / 64, 256, 0, stream>>>(aggb_u, h_u, WtA_u, WtB_u, bias_u, pu_b, NUV);
  // edge classifier: gather + relu + dot
  k_edge<<<(ETV + 255) / 256, 256, 0, stream>>>((const u32*)pu_b, (const u32*)pm_b,
                                                row_t, col_t, Wc2, bc2, out);
}

// Round 7
// 414.661 us; speedup vs baseline: 3.3418x; 1.2800x over previous
//
#include <hip/hip_runtime.h>
#include <hip/hip_bf16.h>

// Hetero-SAGE: rank-fused CSR + merged latency-bound launches + bf16-MFMA GEMMs
// with folded classifier (layer-2 linear => z@Wc1 folded into layer-2 weights).
#define NUV 100000
#define NMV 20000
#define NEV 1000000
#define ETV 500000

#define SCHUNK 4096
#define NCHA 5    // ceil(20000/4096)
#define NCHB 25   // ceil(100000/4096)
#define MBLK 5000   // merchant agg blocks (NMV/4)
#define G1MB 625    // merchant layer-1 gemm blocks (NMV/32)
#define G2MB 313    // merchant layer-2 gemm blocks (ceil(NMV/64))

typedef unsigned short u16;
typedef unsigned int u32;
typedef __attribute__((ext_vector_type(8))) short s16x8;
typedef __attribute__((ext_vector_type(4))) float f32x4;
typedef __attribute__((ext_vector_type(4))) unsigned short u16x4;
typedef __attribute__((ext_vector_type(4))) unsigned int u32x4;

__device__ inline u16 bf16r(float f) {  // RTNE float->bf16
  u32 b = __builtin_bit_cast(u32, f);
  u32 r = b + 0x7fffu + ((b >> 16) & 1u);
  return (u16)(r >> 16);
}
__device__ inline float bflo(u32 v) { return __builtin_bit_cast(float, v << 16); }
__device__ inline float bfhi(u32 v) { return __builtin_bit_cast(float, v & 0xffff0000u); }

#define GLOAD_LDS16(src, dst) \
  __builtin_amdgcn_global_load_lds((const __attribute__((address_space(1))) void*)(src), \
                                   (__attribute__((address_space(3))) void*)(dst), 16, 0, 0)

// ---------------- CSR: fused histogram + rank (atomic return = rank) ----------------
__global__ __launch_bounds__(256) void k_hist_rank(
    const int* __restrict__ col_um, int* __restrict__ off_um, int* __restrict__ rank_um,
    const int* __restrict__ col_mu, int* __restrict__ off_mu, int* __restrict__ rank_mu) {
  int i = (blockIdx.x * 256 + threadIdx.x) * 4;
  if (i >= 2 * NEV) return;
  bool um = i < NEV;
  const int* col = um ? col_um : col_mu;
  int* off = um ? off_um : off_mu;
  int* rank = um ? rank_um : rank_mu;
  int lo = um ? i : i - NEV;
  int4 c = *(const int4*)(col + lo);
  int4 k;
  k.x = atomicAdd(&off[c.x + 1], 1);
  k.y = atomicAdd(&off[c.y + 1], 1);
  k.z = atomicAdd(&off[c.z + 1], 1);
  k.w = atomicAdd(&off[c.w + 1], 1);
  *(int4*)(rank + lo) = k;
}

// ---- multi-block scan: p1 chunk sums, p2 chunk-offset scan, p3 final ----
__global__ __launch_bounds__(1024) void k_scan_p1(const int* __restrict__ offA, int nA,
                                                  const int* __restrict__ offB, int nB,
                                                  int* __restrict__ bsum) {
  int b = blockIdx.x;
  const int* off; int n; int c;
  if (b < NCHA) { off = offA + 1; n = nA; c = b; }
  else          { off = offB + 1; n = nB; c = b - NCHA; }
  __shared__ int wsum[16];
  int tid = threadIdx.x, lane = tid & 63, w = tid >> 6;
  int base = c * SCHUNK + tid * 4;
  int s = 0;
  #pragma unroll
  for (int q = 0; q < 4; ++q) s += (base + q < n) ? off[base + q] : 0;
  #pragma unroll
  for (int d = 1; d < 64; d <<= 1) s += __shfl_xor(s, d);
  if (lane == 0) wsum[w] = s;
  __syncthreads();
  if (tid == 0) {
    int tot = 0;
    #pragma unroll
    for (int i = 0; i < 16; ++i) tot += wsum[i];
    bsum[b] = tot;
  }
}

__global__ __launch_bounds__(64) void k_scan_p2(int* __restrict__ bsum) {
  int lane = threadIdx.x;
  int v = 0;
  if (lane < NCHA) v = bsum[lane];
  else if (lane >= 32 && lane < 32 + NCHB) v = bsum[NCHA + lane - 32];
  int s = v;
  #pragma unroll
  for (int d = 1; d < 32; d <<= 1) { int t = __shfl_up(s, d, 32); if ((lane & 31) >= d) s += t; }
  int ex = s - v;
  if (lane < NCHA) bsum[lane] = ex;
  else if (lane >= 32 && lane < 32 + NCHB) bsum[NCHA + lane - 32] = ex;
}

__global__ __launch_bounds__(1024) void k_scan_p3(int* __restrict__ offA, int nA,
                                                  int* __restrict__ offB, int nB,
                                                  const int* __restrict__ bsum) {
  int b = blockIdx.x;
  int* off; int n; int c;
  if (b < NCHA) { off = offA + 1; n = nA; c = b; }
  else          { off = offB + 1; n = nB; c = b - NCHA; }
  int carry = bsum[b];
  __shared__ int wsum[16];
  int tid = threadIdx.x, lane = tid & 63, w = tid >> 6;
  int base = c * SCHUNK + tid * 4;
  int v[4];
  #pragma unroll
  for (int q = 0; q < 4; ++q) v[q] = (base + q < n) ? off[base + q] : 0;
  int p1 = v[0] + v[1], p2 = p1 + v[2], p3 = p2 + v[3];
  int s = p3, sc = s;
  #pragma unroll
  for (int d = 1; d < 64; d <<= 1) { int t = __shfl_up(sc, d); if (lane >= d) sc += t; }
  if (lane == 63) wsum[w] = sc;
  __syncthreads();
  if (w == 0 && lane < 16) {
    int ws_ = wsum[lane];
    #pragma unroll
    for (int d = 1; d < 16; d <<= 1) { int t = __shfl_up(ws_, d, 16); if (lane >= d) ws_ += t; }
    wsum[lane] = ws_;
  }
  __syncthreads();
  int ex = sc - s + (w ? wsum[w - 1] : 0) + carry;
  if (base + 0 < n) off[base + 0] = ex + v[0];
  if (base + 1 < n) off[base + 1] = ex + p1;
  if (base + 2 < n) off[base + 2] = ex + p2;
  if (base + 3 < n) off[base + 3] = ex + p3;
}

// ---------------- atomic-free scatter (uses precomputed ranks) ----------------
__global__ __launch_bounds__(256) void k_scatter2(
    const int* __restrict__ col_um, const int* __restrict__ row_um,
    const int* __restrict__ rank_um, const int* __restrict__ off_um, int* __restrict__ srow_um,
    const int* __restrict__ col_mu, const int* __restrict__ row_mu,
    const int* __restrict__ rank_mu, const int* __restrict__ off_mu, int* __restrict__ srow_mu) {
  int i = (blockIdx.x * 256 + threadIdx.x) * 4;
  if (i >= 2 * NEV) return;
  bool um = i < NEV;
  const int* col = um ? col_um : col_mu;
  const int* row = um ? row_um : row_mu;
  const int* rank = um ? rank_um : rank_mu;
  const int* off = um ? off_um : off_mu;
  int* srow = um ? srow_um : srow_mu;
  int lo = um ? i : i - NEV;
  int4 c = *(const int4*)(col + lo);
  int4 r = *(const int4*)(row + lo);
  int4 k = *(const int4*)(rank + lo);
  srow[off[c.x] + k.x] = r.x;
  srow[off[c.y] + k.y] = r.y;
  srow[off[c.z] + k.z] = r.z;
  srow[off[c.w] + k.w] = r.w;
}

// ---------------- x_user -> bf16 (halves layer-1 gather traffic) ----------------
__global__ __launch_bounds__(256) void k_xub(const float* __restrict__ in, u32* __restrict__ o, int n8) {
  int stride = gridDim.x * 256;
  for (int i = blockIdx.x * 256 + threadIdx.x; i < n8; i += stride) {
    float4 a = *(const float4*)(in + (size_t)i * 8);
    float4 b = *(const float4*)(in + (size_t)i * 8 + 4);
    u32x4 r;
    r[0] = (u32)bf16r(a.x) | ((u32)bf16r(a.y) << 16);
    r[1] = (u32)bf16r(a.z) | ((u32)bf16r(a.w) << 16);
    r[2] = (u32)bf16r(b.x) | ((u32)bf16r(b.y) << 16);
    r[3] = (u32)bf16r(b.z) | ((u32)bf16r(b.w) << 16);
    *(u32x4*)(o + (size_t)i * 4) = r;
  }
}

// ---------------- merged layer-1 segment-mean ----------------
// blocks [0,MBLK): merchant dests (bf16 x_user gather, 64 feats)
// blocks [MBLK,MBLK+25000): user dests (fp32 x_merch gather, 32 feats)
__global__ __launch_bounds__(256) void k_agg_l1(
    const int* __restrict__ off_um, const int* __restrict__ srow_um,
    const u32* __restrict__ xub, float* __restrict__ agg_m,
    const int* __restrict__ off_mu, const int* __restrict__ srow_mu,
    const float* __restrict__ xm, float* __restrict__ agg_u) {
  int bid = blockIdx.x, tid = threadIdx.x;
  int lane = tid & 63;
  int half = lane >> 5, f = lane & 31;
  if (bid < MBLK) {
    int wid = (bid * 256 + tid) >> 6;
    int s = off_um[wid], t = off_um[wid + 1];
    float ax[4] = {}, ay[4] = {};
    int j = s + half;
    for (; j + 8 <= t; j += 8) {
      int r[4];
      #pragma unroll
      for (int q = 0; q < 4; ++q) r[q] = srow_um[j + 2 * q];
      u32 v[4];
      #pragma unroll
      for (int q = 0; q < 4; ++q) v[q] = xub[(size_t)r[q] * 32 + f];
      #pragma unroll
      for (int q = 0; q < 4; ++q) { ax[q] += bflo(v[q]); ay[q] += bfhi(v[q]); }
    }
    for (; j < t; j += 2) {
      u32 v = xub[(size_t)srow_um[j] * 32 + f];
      ax[0] += bflo(v); ay[0] += bfhi(v);
    }
    float sx = (ax[0] + ax[1]) + (ax[2] + ax[3]);
    float sy = (ay[0] + ay[1]) + (ay[2] + ay[3]);
    sx += __shfl_xor(sx, 32);
    sy += __shfl_xor(sy, 32);
    if (half == 0) {
      float inv = 1.f / (float)max(t - s, 1);
      ((float2*)agg_m)[(size_t)wid * 32 + f] = make_float2(sx * inv, sy * inv);
    }
  } else {
    int wid = ((bid - MBLK) * 256 + tid) >> 6;
    int s = off_mu[wid], t = off_mu[wid + 1];
    float a[4] = {};
    int j = s + half;
    for (; j + 8 <= t; j += 8) {
      int r[4];
      #pragma unroll
      for (int q = 0; q < 4; ++q) r[q] = srow_mu[j + 2 * q];
      #pragma unroll
      for (int q = 0; q < 4; ++q) a[q] += xm[(size_t)r[q] * 32 + f];
    }
    for (; j < t; j += 2) a[0] += xm[(size_t)srow_mu[j] * 32 + f];
    float acc = (a[0] + a[1]) + (a[2] + a[3]);
    acc += __shfl_xor(acc, 32);
    if (half == 0) agg_u[(size_t)wid * 32 + f] = acc / (float)max(t - s, 1);
  }
}

// ---------------- merged layer-2 segment-mean (bf16 gather, fp32 accum, bf16 out) ----------------
__global__ __launch_bounds__(256) void k_agg_l2(
    const int* __restrict__ off_um, const int* __restrict__ srow_um,
    const u16* __restrict__ h_u, u16* __restrict__ aggb_m,
    const int* __restrict__ off_mu, const int* __restrict__ srow_mu,
    const u16* __restrict__ h_m, u16* __restrict__ aggb_u) {
  int bid = blockIdx.x, tid = threadIdx.x;
  int lane = tid & 63;
  const int* off; const int* srow; const u32* x; u32* ag; int wid;
  if (bid < MBLK) {
    off = off_um; srow = srow_um; x = (const u32*)h_u; ag = (u32*)aggb_m;
    wid = (bid * 256 + tid) >> 6;
  } else {
    off = off_mu; srow = srow_mu; x = (const u32*)h_m; ag = (u32*)aggb_u;
    wid = ((bid - MBLK) * 256 + tid) >> 6;
  }
  int s = off[wid], t = off[wid + 1];
  float ax[4] = {}, ay[4] = {};
  int j = s;
  for (; j + 8 <= t; j += 8) {
    int r[8];
    #pragma unroll
    for (int q = 0; q < 8; ++q) r[q] = srow[j + q];
    u32 v[8];
    #pragma unroll
    for (int q = 0; q < 8; ++q) v[q] = x[(size_t)r[q] * 64 + lane];
    #pragma unroll
    for (int q = 0; q < 8; ++q) { ax[q & 3] += bflo(v[q]); ay[q & 3] += bfhi(v[q]); }
  }
  for (; j < t; ++j) {
    u32 v = x[(size_t)srow[j] * 64 + lane];
    ax[0] += bflo(v); ay[0] += bfhi(v);
  }
  float sx = (ax[0] + ax[1]) + (ax[2] + ax[3]);
  float sy = (ay[0] + ay[1]) + (ay[2] + ay[3]);
  float inv = 1.f / (float)max(t - s, 1);
  ag[(size_t)wid * 64 + lane] = (u32)bf16r(sx * inv) | ((u32)bf16r(sy * inv) << 16);
}

// ---------------- layer-1 dual GEMM body (fp32 in, bf16 out) ----------------
template <int KA, int KB>
__device__ inline void gemm1_body(const float* __restrict__ A, const float* __restrict__ B,
                                  const float* __restrict__ Wa, const float* __restrict__ Wb,
                                  const float* __restrict__ bias, u16* __restrict__ outb,
                                  int m0, float* At, float* Bt) {
  int tid = threadIdx.x;
  {
    int m = tid & 31, kq = tid >> 5;
    const float* Ar = A + (size_t)(m0 + m) * KA;
    for (int k0 = kq * 4; k0 < KA; k0 += 32) {
      float4 v = *(const float4*)(Ar + k0);
      At[(k0 + 0) * 32 + m] = v.x; At[(k0 + 1) * 32 + m] = v.y;
      At[(k0 + 2) * 32 + m] = v.z; At[(k0 + 3) * 32 + m] = v.w;
    }
    const float* Br = B + (size_t)(m0 + m) * KB;
    for (int k0 = kq * 4; k0 < KB; k0 += 32) {
      float4 v = *(const float4*)(Br + k0);
      Bt[(k0 + 0) * 32 + m] = v.x; Bt[(k0 + 1) * 32 + m] = v.y;
      Bt[(k0 + 2) * 32 + m] = v.z; Bt[(k0 + 3) * 32 + m] = v.w;
    }
  }
  __syncthreads();
  int tx = tid & 31, ty = tid >> 5;
  float acc[4][4] = {};
  #pragma unroll 4
  for (int k = 0; k < KA; ++k) {
    float4 wv = *(const float4*)(Wa + k * 128 + tx * 4);
    float4 av = *(const float4*)(&At[k * 32 + ty * 4]);
    float am[4] = {av.x, av.y, av.z, av.w};
    float wo[4] = {wv.x, wv.y, wv.z, wv.w};
    #pragma unroll
    for (int mi = 0; mi < 4; ++mi)
      #pragma unroll
      for (int oi = 0; oi < 4; ++oi) acc[mi][oi] += am[mi] * wo[oi];
  }
  #pragma unroll 4
  for (int k = 0; k < KB; ++k) {
    float4 wv = *(const float4*)(Wb + k * 128 + tx * 4);
    float4 av = *(const float4*)(&Bt[k * 32 + ty * 4]);
    float am[4] = {av.x, av.y, av.z, av.w};
    float wo[4] = {wv.x, wv.y, wv.z, wv.w};
    #pragma unroll
    for (int mi = 0; mi < 4; ++mi)
      #pragma unroll
      for (int oi = 0; oi < 4; ++oi) acc[mi][oi] += am[mi] * wo[oi];
  }
  float4 bv = *(const float4*)(bias + tx * 4);
  float bb[4] = {bv.x, bv.y, bv.z, bv.w};
  #pragma unroll
  for (int mi = 0; mi < 4; ++mi) {
    u16x4 o;
    #pragma unroll
    for (int oi = 0; oi < 4; ++oi) {
      float v = acc[mi][oi] + bb[oi];
      v = v > 0.f ? v : 0.f;  // layer-1 relu
      o[oi] = bf16r(v);
    }
    *(u16x4*)(outb + (size_t)(m0 + ty * 4 + mi) * 128 + tx * 4) = o;
  }
}

// merged layer-1 GEMM: blocks [0,G1MB) merchant <64,32>, rest user <32,64>
__global__ __launch_bounds__(256) void k_gemm1(
    const float* __restrict__ agg_m, const float* __restrict__ x_merch,
    const float* __restrict__ W1l_um, const float* __restrict__ W1r_um,
    const float* __restrict__ b1_um, u16* __restrict__ h_m,
    const float* __restrict__ agg_u, const float* __restrict__ x_user,
    const float* __restrict__ W1l_mu, const float* __restrict__ W1r_mu,
    const float* __restrict__ b1_mu, u16* __restrict__ h_u) {
  __shared__ float At[64 * 32];
  __shared__ float Bt[64 * 32];
  int bid = blockIdx.x;
  if (bid < G1MB)
    gemm1_body<64, 32>(agg_m, x_merch, W1l_um, W1r_um, b1_um, h_m, bid * 32, At, Bt);
  else
    gemm1_body<32, 64>(agg_u, x_user, W1l_mu, W1r_mu, b1_mu, h_u, (bid - G1MB) * 32, At, Bt);
}

// ---------------- combined-weight prep: Wt = (W2 @ Wc1half)^T in bf16, plus folded biases ----------------
__global__ __launch_bounds__(256) void k_prep_comb(
    const float* __restrict__ W2l_um, const float* __restrict__ W2r_um,
    const float* __restrict__ W2l_mu, const float* __restrict__ W2r_mu,
    const float* __restrict__ b2_um, const float* __restrict__ b2_mu,
    const float* __restrict__ Wc1, const float* __restrict__ bc1,
    u16* __restrict__ WtA_u, u16* __restrict__ WtB_u,
    u16* __restrict__ WtA_m, u16* __restrict__ WtB_m,
    float* __restrict__ bias_u, float* __restrict__ bias_m) {
  int t = blockIdx.x * 256 + threadIdx.x;
  if (t < 65536) {
    int mat = t >> 14, rem = t & 16383;
    int o = rem >> 7, k = rem & 127;
    const float* W2 = mat == 0 ? W2l_mu : mat == 1 ? W2r_mu : mat == 2 ? W2l_um : W2r_um;
    const float* wc = Wc1 + (mat >= 2 ? 128 * 128 : 0) + o;
    float s = 0.f;
    #pragma unroll 4
    for (int j = 0; j < 128; ++j) s += W2[k * 128 + j] * wc[j * 128];
    u16* dst = mat == 0 ? WtA_u : mat == 1 ? WtB_u : mat == 2 ? WtA_m : WtB_m;
    dst[o * 128 + k] = bf16r(s);
  } else if (t < 65536 + 256) {
    int r = t - 65536;
    int o = r & 127;
    if (r < 128) {
      float s = 0.f;
      for (int j = 0; j < 128; ++j) s += b2_mu[j] * Wc1[j * 128 + o];
      bias_u[o] = s;
    } else {
      float s = bc1[o];  // fold bc1 into merchant-side bias
      for (int j = 0; j < 128; ++j) s += b2_um[j] * Wc1[(128 + j) * 128 + o];
      bias_m[o] = s;
    }
  }
}

// ---------------- merged layer-2 GEMM (bf16 MFMA): outb = bf16(aggb@Wtl + hb@Wtr + bias) ----------------
__global__ __launch_bounds__(256) void k_gemm2_mfma(
    const u16* __restrict__ aggb_m, const u16* __restrict__ h_m,
    const u16* __restrict__ WtA_m, const u16* __restrict__ WtB_m,
    const float* __restrict__ bias_m, u16* __restrict__ pm_b,
    const u16* __restrict__ aggb_u, const u16* __restrict__ h_u,
    const u16* __restrict__ WtA_u, const u16* __restrict__ WtB_u,
    const float* __restrict__ bias_u, u16* __restrict__ pu_b) {
  __shared__ u16 Zs[64 * 256];  // 32KB
  int tid = threadIdx.x;
  int bid = blockIdx.x;
  const u16 *aggb, *hb, *Wtl, *Wtr; const float* bias; u16* zb; int nd, r0;
  if (bid < G2MB) {
    aggb = aggb_m; hb = h_m; Wtl = WtA_m; Wtr = WtB_m; bias = bias_m; zb = pm_b;
    nd = NMV; r0 = bid * 64;
  } else {
    aggb = aggb_u; hb = h_u; Wtl = WtA_u; Wtr = WtB_u; bias = bias_u; zb = pu_b;
    nd = NUV; r0 = (bid - G2MB) * 64;
  }
  {
    int half = (tid >> 4) & 1;
    const u16* tab = half ? hb : aggb;
    #pragma unroll
    for (int it = 0; it < 8; ++it) {
      int q = tid + it * 256;
      int rl = q >> 5;
      int cc = (q & 15) ^ (rl & 7);
      int r = r0 + rl; r = r < nd ? r : nd - 1;
      const u16* src = tab + (size_t)r * 128 + cc * 8;
      u16* dst = Zs + (tid >> 6) * 512 + it * 2048;
      GLOAD_LDS16(src, dst);
    }
  }
  __syncthreads();
  int l = tid & 63, wv = tid >> 6;
  int lg = l >> 4, lr = l & 15;
  f32x4 acc[4][2];
  #pragma unroll
  for (int mt = 0; mt < 4; ++mt)
    #pragma unroll
    for (int c = 0; c < 2; ++c) acc[mt][c] = (f32x4){0.f, 0.f, 0.f, 0.f};
  #pragma unroll
  for (int cti = 0; cti < 2; ++cti) {
    int o = (wv * 2 + cti) * 16 + lr;
    const u16* wpl = Wtl + (size_t)o * 128 + lg * 8;
    const u16* wpr = Wtr + (size_t)o * 128 + lg * 8;
    s16x8 b[8];
    #pragma unroll
    for (int ks = 0; ks < 4; ++ks) b[ks] = *(const s16x8*)(wpl + ks * 32);
    #pragma unroll
    for (int ks = 0; ks < 4; ++ks) b[ks + 4] = *(const s16x8*)(wpr + ks * 32);
    #pragma unroll
    for (int mt = 0; mt < 4; ++mt) {
      int rl = mt * 16 + lr;
      int rb = rl * 512, sw = (rl & 7) << 4;
      #pragma unroll
      for (int ks = 0; ks < 8; ++ks) {
        s16x8 a = *(const s16x8*)((const char*)Zs + ((rb + ks * 64 + lg * 16) ^ sw));
        acc[mt][cti] = __builtin_amdgcn_mfma_f32_16x16x32_bf16(a, b[ks], acc[mt][cti], 0, 0, 0);
      }
    }
  }
  float bv[2];
  #pragma unroll
  for (int cti = 0; cti < 2; ++cti) bv[cti] = bias[(wv * 2 + cti) * 16 + lr];
  #pragma unroll
  for (int mt = 0; mt < 4; ++mt)
    #pragma unroll
    for (int cti = 0; cti < 2; ++cti) {
      int o = (wv * 2 + cti) * 16 + lr;
      #pragma unroll
      for (int rg = 0; rg < 4; ++rg) {
        int r = r0 + mt * 16 + lg * 4 + rg;
        if (r < nd) zb[(size_t)r * 128 + o] = bf16r(acc[mt][cti][rg] + bv[cti]);
      }
    }
}

// ---------------- edge op: out[e] = Wc2 . relu(pu[row_t[e]] + pm[col_t[e]]) + bc2 ----------------
// 16-lane groups: one edge per group (u32x4 = full 128-feat row), 4 edges/wave in flight.
__global__ __launch_bounds__(256) void k_edge(
    const u32* __restrict__ pu, const u32* __restrict__ pm,
    const int* __restrict__ row_t, const int* __restrict__ col_t,
    const float* __restrict__ Wc2, const float* __restrict__ bc2,
    float* __restrict__ out) {
  __shared__ float res[256];
  int tid = threadIdx.x, l = tid & 63, wv = tid >> 6;
  int lr = l & 15, g = l >> 4;
  float w2v[8];
  #pragma unroll
  for (int q = 0; q < 8; ++q) w2v[q] = Wc2[lr * 8 + q];
  int base = blockIdx.x * 256 + wv * 64;
  #pragma unroll 2
  for (int it = 0; it < 16; ++it) {
    int e = base + it * 4 + g;
    int ec = e < ETV ? e : ETV - 1;
    int r = row_t[ec], c = col_t[ec];
    u32x4 a = *(const u32x4*)(pu + (size_t)r * 64 + lr * 4);
    u32x4 b = *(const u32x4*)(pm + (size_t)c * 64 + lr * 4);
    float p = 0.f;
    #pragma unroll
    for (int q = 0; q < 4; ++q) {
      float h0 = bflo(a[q]) + bflo(b[q]);
      float h1 = bfhi(a[q]) + bfhi(b[q]);
      h0 = h0 > 0.f ? h0 : 0.f;
      h1 = h1 > 0.f ? h1 : 0.f;
      p += h0 * w2v[2 * q] + h1 * w2v[2 * q + 1];
    }
    p += __shfl_xor(p, 1); p += __shfl_xor(p, 2);
    p += __shfl_xor(p, 4); p += __shfl_xor(p, 8);
    if (lr == 0) res[wv * 64 + it * 4 + g] = p;
  }
  __syncthreads();
  int eo = blockIdx.x * 256 + tid;
  if (eo < ETV) out[eo] = res[tid] + bc2[0];
}

extern "C" void kernel_launch(void* const* d_in, const int* in_sizes, int n_in,
                              void* d_out, int out_size, void* d_ws, size_t ws_size,
                              hipStream_t stream) {
  const float* x_user  = (const float*)d_in[0];
  const float* x_merch = (const float*)d_in[1];
  const int* row_um = (const int*)d_in[2]; const int* col_um = (const int*)d_in[3];
  const int* row_mu = (const int*)d_in[4]; const int* col_mu = (const int*)d_in[5];
  const int* row_t  = (const int*)d_in[6]; const int* col_t  = (const int*)d_in[7];
  const float* W1l_um = (const float*)d_in[8];  const float* W1r_um = (const float*)d_in[9];  const float* b1_um = (const float*)d_in[10];
  const float* W1l_mu = (const float*)d_in[11]; const float* W1r_mu = (const float*)d_in[12]; const float* b1_mu = (const float*)d_in[13];
  const float* W2l_um = (const float*)d_in[14]; const float* W2r_um = (const float*)d_in[15]; const float* b2_um = (const float*)d_in[16];
  const float* W2l_mu = (const float*)d_in[17]; const float* W2r_mu = (const float*)d_in[18]; const float* b2_mu = (const float*)d_in[19];
  const float* Wc1 = (const float*)d_in[20]; const float* bc1 = (const float*)d_in[21];
  const float* Wc2 = (const float*)d_in[22]; const float* bc2 = (const float*)d_in[23];
  float* out = (float*)d_out;

  char* ws = (char*)d_ws;
  size_t p = 0;
  auto alloc = [&](size_t bytes) -> char* {
    char* r = ws + p;
    p = (p + bytes + 255) & ~(size_t)255;
    return r;
  };
  int* off_um = (int*)alloc((size_t)(NMV + 1) * 4);
  int* off_mu = (int*)alloc((size_t)(NUV + 1) * 4);
  size_t zero_end = p;
  int* bsum = (int*)alloc((size_t)(NCHA + NCHB) * 4);
  int* rank_um = (int*)alloc((size_t)NEV * 4);
  int* rank_mu = (int*)alloc((size_t)NEV * 4);
  int* srow_um = (int*)alloc((size_t)NEV * 4);
  int* srow_mu = (int*)alloc((size_t)NEV * 4);
  u32* xub = (u32*)alloc((size_t)NUV * 32 * 4);          // x_user in bf16 (packed pairs)
  float* agg_m = (float*)alloc((size_t)NMV * 64 * 4);    // layer1 merchant agg (fp32, 64 feats)
  float* agg_u = (float*)alloc((size_t)NUV * 32 * 4);    // layer1 user agg (fp32, 32 feats)
  u16* h_m   = (u16*)alloc((size_t)NMV * 128 * 2);       // bf16 hidden
  u16* h_u   = (u16*)alloc((size_t)NUV * 128 * 2);
  u16* aggb_m = (u16*)alloc((size_t)NMV * 128 * 2);      // layer2 agg (bf16)
  u16* aggb_u = (u16*)alloc((size_t)NUV * 128 * 2);
  u16* pm_b  = (u16*)alloc((size_t)NMV * 128 * 2);       // folded classifier projections (bf16)
  u16* pu_b  = (u16*)alloc((size_t)NUV * 128 * 2);
  u16* WtA_u = (u16*)alloc((size_t)128 * 128 * 2);
  u16* WtB_u = (u16*)alloc((size_t)128 * 128 * 2);
  u16* WtA_m = (u16*)alloc((size_t)128 * 128 * 2);
  u16* WtB_m = (u16*)alloc((size_t)128 * 128 * 2);
  float* bias_u = (float*)alloc(128 * 4);
  float* bias_m = (float*)alloc(128 * 4);
  if (p > ws_size) return;  // workspace too small: fail loudly via absmax

  hipMemsetAsync(d_ws, 0, zero_end, stream);
  k_prep_comb<<<257, 256, 0, stream>>>(W2l_um, W2r_um, W2l_mu, W2r_mu, b2_um, b2_mu, Wc1, bc1,
                                       WtA_u, WtB_u, WtA_m, WtB_m, bias_u, bias_m);
  k_xub<<<1024, 256, 0, stream>>>(x_user, xub, NUV * 64 / 8);
  // CSR build: fused hist+rank, 3-phase scan, atomic-free scatter (both edge types merged)
  k_hist_rank<<<(2 * NEV / 4 + 255) / 256, 256, 0, stream>>>(col_um, off_um, rank_um,
                                                             col_mu, off_mu, rank_mu);
  k_scan_p1<<<NCHA + NCHB, 1024, 0, stream>>>(off_um, NMV, off_mu, NUV, bsum);
  k_scan_p2<<<1, 64, 0, stream>>>(bsum);
  k_scan_p3<<<NCHA + NCHB, 1024, 0, stream>>>(off_um, NMV, off_mu, NUV, bsum);
  k_scatter2<<<(2 * NEV / 4 + 255) / 256, 256, 0, stream>>>(
      col_um, row_um, rank_um, off_um, srow_um,
      col_mu, row_mu, rank_mu, off_mu, srow_mu);
  // layer 1 (merged aggs, merged dual GEMMs; bf16 h out)
  k_agg_l1<<<MBLK + NUV / 4, 256, 0, stream>>>(off_um, srow_um, xub, agg_m,
                                               off_mu, srow_mu, x_merch, agg_u);
  k_gemm1<<<G1MB + NUV / 32, 256, 0, stream>>>(agg_m, x_merch, W1l_um, W1r_um, b1_um, h_m,
                                               agg_u, x_user, W1l_mu, W1r_mu, b1_mu, h_u);
  // layer 2 (merged aggs, merged MFMA GEMMs with folded classifier weights)
  k_agg_l2<<<MBLK + NUV / 4, 256, 0, stream>>>(off_um, srow_um, h_u, aggb_m,
                                               off_mu, srow_mu, h_m, aggb_u);
  k_gemm2_mfma<<<G2MB + (NUV + 63) / 64, 256, 0, stream>>>(
      aggb_m, h_m, WtA_m, WtB_m, bias_m, pm_b,
      aggb_u, h_u, WtA_u, WtB_u, bias_u, pu_b);
  // edge classifier: gather + relu + dot
  k_edge<<<(ETV + 255) / 256, 256, 0, stream>>>((const u32*)pu_b, (const u32*)pm_b,
                                                row_t, col_t, Wc2, bc2, out);
}